// Round 5
// baseline (1293.775 us; speedup 1.0000x reference)
//
#include <hip/hip_runtime.h>

// ChebNet K=3 on 100K nodes / 1.6M edges, f32 I/O.
// x -> ChebConv(W1) -> relu -> dropout(0.5, jax key 42, partitionable threefry)
//   -> ChebConv(W2) -> log_softmax -> out[N,32]
// prop(h)[v] = -dinv[v] * sum_{e in row v} dinv[col_e] * h[col_e]   (norm factored)
// Tx2 terms fused into dense kernels (no T2 buffer). ws ~59 MB.
// Dropout word: JAX partitionable mode returns bits1 ^ bits2 for 32-bit draws.

static constexpr int BLK = 256;

__device__ __forceinline__ unsigned rotl32(unsigned x, int r) {
    return (x << r) | (x >> (32 - r));
}

// JAX partitionable threefry random word for element i:
// (b1,b2) = threefry2x32(key=(0,42), counter=(hi=0, lo=i)); word = b1 ^ b2.
__device__ __forceinline__ unsigned tf_word(unsigned i) {
    const unsigned ks0 = 0u;
    const unsigned ks1 = 42u;
    const unsigned ks2 = 0u ^ 42u ^ 0x1BD11BDAu;
    unsigned x0 = 0u + ks0;
    unsigned x1 = i + ks1;
#define TF_RND(r) { x0 += x1; x1 = rotl32(x1, (r)); x1 ^= x0; }
    TF_RND(13) TF_RND(15) TF_RND(26) TF_RND(6)
    x0 += ks1; x1 += ks2 + 1u;
    TF_RND(17) TF_RND(29) TF_RND(16) TF_RND(24)
    x0 += ks2; x1 += ks0 + 2u;
    TF_RND(13) TF_RND(15) TF_RND(26) TF_RND(6)
    x0 += ks0; x1 += ks1 + 3u;
    TF_RND(17) TF_RND(29) TF_RND(16) TF_RND(24)
    x0 += ks1; x1 += ks2 + 4u;
    TF_RND(13) TF_RND(15) TF_RND(26) TF_RND(6)
    x0 += ks2; x1 += ks0 + 5u;
#undef TF_RND
    return x0 ^ x1;
}

// flags[0] = 1 if edge_index stored as int64 (odd int32 words all zero).
__global__ void k_detect(const int* __restrict__ ei, int* __restrict__ flags) {
    __shared__ int cnt_nz;
    int t = threadIdx.x;
    if (t == 0) cnt_nz = 0;
    __syncthreads();
    if (ei[2 * t + 1] != 0) atomicAdd(&cnt_nz, 1);
    __syncthreads();
    if (t == 0) flags[0] = (cnt_nz == 0) ? 1 : 0;
}

__global__ void k_hist(const int* __restrict__ ei, int E,
                       const int* __restrict__ flags, int* __restrict__ deg) {
    int e = blockIdx.x * blockDim.x + threadIdx.x;
    if (e >= E) return;
    int r = flags[0] ? ei[2 * e] : ei[e];
    atomicAdd(&deg[r], 1);
}

__global__ void k_dinv(const int* __restrict__ deg, int N, float* __restrict__ dinv) {
    int v = blockIdx.x * blockDim.x + threadIdx.x;
    if (v < N) {
        int d = deg[v];
        dinv[v] = (d > 0) ? (1.0f / sqrtf((float)d)) : 0.0f;
    }
}

// Single-block exclusive scan of deg -> row_ptr (+ cursor copy).
__global__ void k_scan(const int* __restrict__ deg, int N, int E,
                       int* __restrict__ row_ptr, int* __restrict__ cursor) {
    __shared__ int sums[1024];
    int t = threadIdx.x;
    int per = (N + 1023) >> 10;
    int beg = t * per;
    int end = min(N, beg + per);
    int s = 0;
    for (int i = beg; i < end; ++i) s += deg[i];
    sums[t] = s;
    __syncthreads();
    for (int off = 1; off < 1024; off <<= 1) {
        int val = (t >= off) ? sums[t - off] : 0;
        __syncthreads();
        sums[t] += val;
        __syncthreads();
    }
    int run = (t == 0) ? 0 : sums[t - 1];
    for (int i = beg; i < end; ++i) {
        row_ptr[i] = run;
        cursor[i] = run;
        run += deg[i];
    }
    if (t == 1023) row_ptr[N] = E;
}

__global__ void k_build(const int* __restrict__ ei, int E,
                        const int* __restrict__ flags, int* __restrict__ cursor,
                        int* __restrict__ sdst) {
    int e = blockIdx.x * blockDim.x + threadIdx.x;
    if (e >= E) return;
    int r, c;
    if (flags[0]) { r = ei[2 * e]; c = ei[2 * (E + e)]; }
    else          { r = ei[e];     c = ei[E + e]; }
    int p = atomicAdd(&cursor[r], 1);
    sdst[p] = c;
}

// dst[v][f] = -dinv[v] * sum_e dinv[c]*src[c][f]
__global__ void __launch_bounds__(BLK) k_prop(const float* __restrict__ src,
                                              const float* __restrict__ dinv,
                                              const int* __restrict__ row_ptr,
                                              const int* __restrict__ sdst,
                                              int N, float* __restrict__ dst) {
    int v = blockIdx.x * (BLK >> 6) + (threadIdx.x >> 6);
    int f = threadIdx.x & 63;
    if (v >= N) return;
    int beg = row_ptr[v];
    int end = row_ptr[v + 1];
    float acc = 0.0f;
    for (int e = beg; e < end; ++e) {
        int c = sdst[e];
        acc = fmaf(dinv[c], src[(size_t)c * 64 + f], acc);
    }
    dst[(size_t)v * 64 + f] = -dinv[v] * acc;
}

// Layer 1 fused: Tx2 = 2*prop(T1)-x computed in-kernel.
// H = dropout(relu(x@W1[0] + T1@W1[1] + Tx2@W1[2] + b1)). One wave per node.
__global__ void __launch_bounds__(BLK) k_dense1(const float* __restrict__ x,
                                                const float* __restrict__ T1,
                                                const float* __restrict__ dinv,
                                                const int* __restrict__ row_ptr,
                                                const int* __restrict__ sdst,
                                                const float* __restrict__ W1,
                                                const float* __restrict__ b1,
                                                int N, float* __restrict__ H) {
    __shared__ float s0[BLK], s1[BLK], s2[BLK];
    int tid = threadIdx.x;
    int wid = tid >> 6;
    int j = tid & 63;
    int v = blockIdx.x * 4 + wid;
    if (v > N - 1) v = N - 1;  // never triggers for N%4==0 grids
    size_t base = (size_t)v * 64;
    float xv = x[base + j];
    s0[tid] = xv;
    s1[tid] = T1[base + j];
    int beg = row_ptr[v];
    int end = row_ptr[v + 1];
    float acc = 0.0f;
    for (int e = beg; e < end; ++e) {
        int c = sdst[e];
        acc = fmaf(dinv[c], T1[(size_t)c * 64 + j], acc);
    }
    // tx2 = 2*(-dinv[v]*acc) - xv
    s2[tid] = fmaf(-2.0f * dinv[v], acc, -xv);
    __syncthreads();
    const float* a0 = &s0[wid * 64];
    const float* a1 = &s1[wid * 64];
    const float* a2 = &s2[wid * 64];
    float o = b1[j];
#pragma unroll 8
    for (int k = 0; k < 64; ++k) {
        o = fmaf(a0[k], W1[k * 64 + j], o);
        o = fmaf(a1[k], W1[4096 + k * 64 + j], o);
        o = fmaf(a2[k], W1[8192 + k * 64 + j], o);
    }
    o = fmaxf(o, 0.0f);
    unsigned bits = tf_word((unsigned)v * 64u + (unsigned)j);
    H[base + j] = (bits & 0x80000000u) ? 0.0f : o * 2.0f;  // keep iff MSB==0; /0.5
}

// Layer 2 fused: Tx2' = 2*prop(T1')-H; out = log_softmax(H@W2[0]+T1'@W2[1]+Tx2'@W2[2]+b2).
// One wave per node; lanes 32-63 duplicate lanes 0-31 in the matmul, only <32 write.
__global__ void __launch_bounds__(BLK) k_dense2(const float* __restrict__ H,
                                                const float* __restrict__ T1,
                                                const float* __restrict__ dinv,
                                                const int* __restrict__ row_ptr,
                                                const int* __restrict__ sdst,
                                                const float* __restrict__ W2,
                                                const float* __restrict__ b2,
                                                int N, float* __restrict__ out) {
    __shared__ float s0[BLK], s1[BLK], s2[BLK];
    int tid = threadIdx.x;
    int wid = tid >> 6;
    int j = tid & 63;
    int v = blockIdx.x * 4 + wid;
    if (v > N - 1) v = N - 1;
    size_t base = (size_t)v * 64;
    float hv = H[base + j];
    s0[tid] = hv;
    s1[tid] = T1[base + j];
    int beg = row_ptr[v];
    int end = row_ptr[v + 1];
    float acc = 0.0f;
    for (int e = beg; e < end; ++e) {
        int c = sdst[e];
        acc = fmaf(dinv[c], T1[(size_t)c * 64 + j], acc);
    }
    s2[tid] = fmaf(-2.0f * dinv[v], acc, -hv);
    __syncthreads();
    const float* a0 = &s0[wid * 64];
    const float* a1 = &s1[wid * 64];
    const float* a2 = &s2[wid * 64];
    int jc = j & 31;
    float o = b2[jc];
#pragma unroll 8
    for (int k = 0; k < 64; ++k) {
        o = fmaf(a0[k], W2[k * 32 + jc], o);
        o = fmaf(a1[k], W2[2048 + k * 32 + jc], o);
        o = fmaf(a2[k], W2[4096 + k * 32 + jc], o);
    }
    // both 32-lane halves hold identical values; reduce within halves
    float m = o;
    for (int d = 16; d >= 1; d >>= 1) m = fmaxf(m, __shfl_xor(m, d));
    float e = expf(o - m);
    float s = e;
    for (int d = 16; d >= 1; d >>= 1) s += __shfl_xor(s, d);
    float r = o - m - logf(s);
    if (j < 32) out[(size_t)v * 32 + jc] = r;
}

extern "C" void kernel_launch(void* const* d_in, const int* in_sizes, int n_in,
                              void* d_out, int out_size, void* d_ws, size_t ws_size,
                              hipStream_t stream) {
    const float* x  = (const float*)d_in[0];
    const int* ei   = (const int*)d_in[1];
    const float* W1 = (const float*)d_in[2];
    const float* b1 = (const float*)d_in[3];
    const float* W2 = (const float*)d_in[4];
    const float* b2 = (const float*)d_in[5];
    float* out = (float*)d_out;

    const int N = in_sizes[0] / 64;
    const int E = in_sizes[1] / 2;

    char* ws = (char*)d_ws;
    size_t off = 0;
    auto alloc = [&](size_t bytes) -> void* {
        void* p = ws + off;
        off = (off + bytes + 511) & ~(size_t)511;
        return p;
    };
    int*   flags   = (int*)alloc(16);
    int*   deg     = (int*)alloc((size_t)N * 4);
    float* dinv    = (float*)alloc((size_t)N * 4);
    int*   row_ptr = (int*)alloc(((size_t)N + 1) * 4);
    int*   cursor  = (int*)alloc((size_t)N * 4);
    int*   sdst    = (int*)alloc((size_t)E * 4);
    float* T1      = (float*)alloc((size_t)N * 64 * 4);
    float* Hb      = (float*)alloc((size_t)N * 64 * 4);
    // total ~59 MB

    hipMemsetAsync(deg, 0, (size_t)N * 4, stream);

    const int gE = (E + BLK - 1) / BLK;
    const int gN = (N + BLK - 1) / BLK;
    const int gW = (N + 3) / 4;  // 4 waves/block, 1 node/wave

    k_detect<<<1, 256, 0, stream>>>(ei, flags);
    k_hist<<<gE, BLK, 0, stream>>>(ei, E, flags, deg);
    k_dinv<<<gN, BLK, 0, stream>>>(deg, N, dinv);
    k_scan<<<1, 1024, 0, stream>>>(deg, N, E, row_ptr, cursor);
    k_build<<<gE, BLK, 0, stream>>>(ei, E, flags, cursor, sdst);

    // Layer 1
    k_prop<<<gW, BLK, 0, stream>>>(x, dinv, row_ptr, sdst, N, T1);
    k_dense1<<<gW, BLK, 0, stream>>>(x, T1, dinv, row_ptr, sdst, W1, b1, N, Hb);

    // Layer 2 (T1 reused for prop(Hb))
    k_prop<<<gW, BLK, 0, stream>>>(Hb, dinv, row_ptr, sdst, N, T1);
    k_dense2<<<gW, BLK, 0, stream>>>(Hb, T1, dinv, row_ptr, sdst, W2, b2, N, out);
}

// Round 6
// 1001.697 us; speedup vs baseline: 1.2916x; 1.2916x over previous
//
#include <hip/hip_runtime.h>

// ChebNet K=3 on 100K nodes / 1.6M edges, f32 I/O.
// x -> ChebConv(W1) -> relu -> dropout(0.5, jax key 42, partitionable threefry)
//   -> ChebConv(W2) -> log_softmax -> out[N,32]
// prop(h)[v] = -dinv[v] * sum_{e in row v} dinv[col_e] * h[col_e]
// Gather loops unrolled x4 (independent accumulators) for memory-level
// parallelism — round-5 counters showed latency-bound (VALUBusy 30%, HBM 11%).

static constexpr int BLK = 256;

__device__ __forceinline__ unsigned rotl32(unsigned x, int r) {
    return (x << r) | (x >> (32 - r));
}

// JAX partitionable threefry word for element i:
// (b1,b2) = threefry2x32(key=(0,42), counter=(0,i)); word = b1 ^ b2.
__device__ __forceinline__ unsigned tf_word(unsigned i) {
    const unsigned ks0 = 0u;
    const unsigned ks1 = 42u;
    const unsigned ks2 = 0u ^ 42u ^ 0x1BD11BDAu;
    unsigned x0 = 0u + ks0;
    unsigned x1 = i + ks1;
#define TF_RND(r) { x0 += x1; x1 = rotl32(x1, (r)); x1 ^= x0; }
    TF_RND(13) TF_RND(15) TF_RND(26) TF_RND(6)
    x0 += ks1; x1 += ks2 + 1u;
    TF_RND(17) TF_RND(29) TF_RND(16) TF_RND(24)
    x0 += ks2; x1 += ks0 + 2u;
    TF_RND(13) TF_RND(15) TF_RND(26) TF_RND(6)
    x0 += ks0; x1 += ks1 + 3u;
    TF_RND(17) TF_RND(29) TF_RND(16) TF_RND(24)
    x0 += ks1; x1 += ks2 + 4u;
    TF_RND(13) TF_RND(15) TF_RND(26) TF_RND(6)
    x0 += ks2; x1 += ks0 + 5u;
#undef TF_RND
    return x0 ^ x1;
}

__global__ void k_detect(const int* __restrict__ ei, int* __restrict__ flags) {
    __shared__ int cnt_nz;
    int t = threadIdx.x;
    if (t == 0) cnt_nz = 0;
    __syncthreads();
    if (ei[2 * t + 1] != 0) atomicAdd(&cnt_nz, 1);
    __syncthreads();
    if (t == 0) flags[0] = (cnt_nz == 0) ? 1 : 0;
}

__global__ void k_hist(const int* __restrict__ ei, int E,
                       const int* __restrict__ flags, int* __restrict__ deg) {
    int e = blockIdx.x * blockDim.x + threadIdx.x;
    if (e >= E) return;
    int r = flags[0] ? ei[2 * e] : ei[e];
    atomicAdd(&deg[r], 1);
}

__global__ void k_dinv(const int* __restrict__ deg, int N, float* __restrict__ dinv) {
    int v = blockIdx.x * blockDim.x + threadIdx.x;
    if (v < N) {
        int d = deg[v];
        dinv[v] = (d > 0) ? (1.0f / sqrtf((float)d)) : 0.0f;
    }
}

__global__ void k_scan(const int* __restrict__ deg, int N, int E,
                       int* __restrict__ row_ptr, int* __restrict__ cursor) {
    __shared__ int sums[1024];
    int t = threadIdx.x;
    int per = (N + 1023) >> 10;
    int beg = t * per;
    int end = min(N, beg + per);
    int s = 0;
    for (int i = beg; i < end; ++i) s += deg[i];
    sums[t] = s;
    __syncthreads();
    for (int off = 1; off < 1024; off <<= 1) {
        int val = (t >= off) ? sums[t - off] : 0;
        __syncthreads();
        sums[t] += val;
        __syncthreads();
    }
    int run = (t == 0) ? 0 : sums[t - 1];
    for (int i = beg; i < end; ++i) {
        row_ptr[i] = run;
        cursor[i] = run;
        run += deg[i];
    }
    if (t == 1023) row_ptr[N] = E;
}

__global__ void k_build(const int* __restrict__ ei, int E,
                        const int* __restrict__ flags, int* __restrict__ cursor,
                        int* __restrict__ sdst) {
    int e = blockIdx.x * blockDim.x + threadIdx.x;
    if (e >= E) return;
    int r, c;
    if (flags[0]) { r = ei[2 * e]; c = ei[2 * (E + e)]; }
    else          { r = ei[e];     c = ei[E + e]; }
    int p = atomicAdd(&cursor[r], 1);
    sdst[p] = c;
}

// Unrolled gather core: returns sum_e dinv[c_e]*src[c_e*64+f] over [beg,end).
__device__ __forceinline__ float gather_row(const float* __restrict__ src,
                                            const float* __restrict__ dinv,
                                            const int* __restrict__ sdst,
                                            int beg, int end, int f) {
    float a0 = 0.0f, a1 = 0.0f, a2 = 0.0f, a3 = 0.0f;
    int e = beg;
    int n4 = beg + ((end - beg) & ~3);
    for (; e < n4; e += 4) {
        int c0 = sdst[e + 0];
        int c1 = sdst[e + 1];
        int c2 = sdst[e + 2];
        int c3 = sdst[e + 3];
        float w0 = dinv[c0], w1 = dinv[c1], w2 = dinv[c2], w3 = dinv[c3];
        float v0 = src[(size_t)c0 * 64 + f];
        float v1 = src[(size_t)c1 * 64 + f];
        float v2 = src[(size_t)c2 * 64 + f];
        float v3 = src[(size_t)c3 * 64 + f];
        a0 = fmaf(w0, v0, a0);
        a1 = fmaf(w1, v1, a1);
        a2 = fmaf(w2, v2, a2);
        a3 = fmaf(w3, v3, a3);
    }
    for (; e < end; ++e) {
        int c = sdst[e];
        a0 = fmaf(dinv[c], src[(size_t)c * 64 + f], a0);
    }
    return (a0 + a1) + (a2 + a3);
}

// dst[v][f] = -dinv[v] * gather
__global__ void __launch_bounds__(BLK) k_prop(const float* __restrict__ src,
                                              const float* __restrict__ dinv,
                                              const int* __restrict__ row_ptr,
                                              const int* __restrict__ sdst,
                                              int N, float* __restrict__ dst) {
    int v = blockIdx.x * (BLK >> 6) + (threadIdx.x >> 6);
    int f = threadIdx.x & 63;
    if (v >= N) return;
    float acc = gather_row(src, dinv, sdst, row_ptr[v], row_ptr[v + 1], f);
    dst[(size_t)v * 64 + f] = -dinv[v] * acc;
}

// Layer 1 fused: Tx2 = 2*prop(T1)-x computed in-kernel.
__global__ void __launch_bounds__(BLK) k_dense1(const float* __restrict__ x,
                                                const float* __restrict__ T1,
                                                const float* __restrict__ dinv,
                                                const int* __restrict__ row_ptr,
                                                const int* __restrict__ sdst,
                                                const float* __restrict__ W1,
                                                const float* __restrict__ b1,
                                                int N, float* __restrict__ H) {
    __shared__ float s0[BLK], s1[BLK], s2[BLK];
    int tid = threadIdx.x;
    int wid = tid >> 6;
    int j = tid & 63;
    int v = blockIdx.x * 4 + wid;
    if (v > N - 1) v = N - 1;
    size_t base = (size_t)v * 64;
    float xv = x[base + j];
    s0[tid] = xv;
    s1[tid] = T1[base + j];
    float acc = gather_row(T1, dinv, sdst, row_ptr[v], row_ptr[v + 1], j);
    s2[tid] = fmaf(-2.0f * dinv[v], acc, -xv);  // tx2
    __syncthreads();
    const float* a0 = &s0[wid * 64];
    const float* a1 = &s1[wid * 64];
    const float* a2 = &s2[wid * 64];
    float o = b1[j];
#pragma unroll 8
    for (int k = 0; k < 64; ++k) {
        o = fmaf(a0[k], W1[k * 64 + j], o);
        o = fmaf(a1[k], W1[4096 + k * 64 + j], o);
        o = fmaf(a2[k], W1[8192 + k * 64 + j], o);
    }
    o = fmaxf(o, 0.0f);
    unsigned bits = tf_word((unsigned)v * 64u + (unsigned)j);
    H[base + j] = (bits & 0x80000000u) ? 0.0f : o * 2.0f;
}

// Layer 2 fused: Tx2' = 2*prop(T1')-H; out = log_softmax(...).
__global__ void __launch_bounds__(BLK) k_dense2(const float* __restrict__ H,
                                                const float* __restrict__ T1,
                                                const float* __restrict__ dinv,
                                                const int* __restrict__ row_ptr,
                                                const int* __restrict__ sdst,
                                                const float* __restrict__ W2,
                                                const float* __restrict__ b2,
                                                int N, float* __restrict__ out) {
    __shared__ float s0[BLK], s1[BLK], s2[BLK];
    int tid = threadIdx.x;
    int wid = tid >> 6;
    int j = tid & 63;
    int v = blockIdx.x * 4 + wid;
    if (v > N - 1) v = N - 1;
    size_t base = (size_t)v * 64;
    float hv = H[base + j];
    s0[tid] = hv;
    s1[tid] = T1[base + j];
    float acc = gather_row(T1, dinv, sdst, row_ptr[v], row_ptr[v + 1], j);
    s2[tid] = fmaf(-2.0f * dinv[v], acc, -hv);
    __syncthreads();
    const float* a0 = &s0[wid * 64];
    const float* a1 = &s1[wid * 64];
    const float* a2 = &s2[wid * 64];
    int jc = j & 31;
    float o = b2[jc];
#pragma unroll 8
    for (int k = 0; k < 64; ++k) {
        o = fmaf(a0[k], W2[k * 32 + jc], o);
        o = fmaf(a1[k], W2[2048 + k * 32 + jc], o);
        o = fmaf(a2[k], W2[4096 + k * 32 + jc], o);
    }
    float m = o;
    for (int d = 16; d >= 1; d >>= 1) m = fmaxf(m, __shfl_xor(m, d));
    float e = expf(o - m);
    float s = e;
    for (int d = 16; d >= 1; d >>= 1) s += __shfl_xor(s, d);
    float r = o - m - logf(s);
    if (j < 32) out[(size_t)v * 32 + jc] = r;
}

extern "C" void kernel_launch(void* const* d_in, const int* in_sizes, int n_in,
                              void* d_out, int out_size, void* d_ws, size_t ws_size,
                              hipStream_t stream) {
    const float* x  = (const float*)d_in[0];
    const int* ei   = (const int*)d_in[1];
    const float* W1 = (const float*)d_in[2];
    const float* b1 = (const float*)d_in[3];
    const float* W2 = (const float*)d_in[4];
    const float* b2 = (const float*)d_in[5];
    float* out = (float*)d_out;

    const int N = in_sizes[0] / 64;
    const int E = in_sizes[1] / 2;

    char* ws = (char*)d_ws;
    size_t off = 0;
    auto alloc = [&](size_t bytes) -> void* {
        void* p = ws + off;
        off = (off + bytes + 511) & ~(size_t)511;
        return p;
    };
    int*   flags   = (int*)alloc(16);
    int*   deg     = (int*)alloc((size_t)N * 4);
    float* dinv    = (float*)alloc((size_t)N * 4);
    int*   row_ptr = (int*)alloc(((size_t)N + 1) * 4);
    int*   cursor  = (int*)alloc((size_t)N * 4);
    int*   sdst    = (int*)alloc((size_t)E * 4);
    float* T1      = (float*)alloc((size_t)N * 64 * 4);
    float* Hb      = (float*)alloc((size_t)N * 64 * 4);

    hipMemsetAsync(deg, 0, (size_t)N * 4, stream);

    const int gE = (E + BLK - 1) / BLK;
    const int gN = (N + BLK - 1) / BLK;
    const int gW = (N + 3) / 4;

    k_detect<<<1, 256, 0, stream>>>(ei, flags);
    k_hist<<<gE, BLK, 0, stream>>>(ei, E, flags, deg);
    k_dinv<<<gN, BLK, 0, stream>>>(deg, N, dinv);
    k_scan<<<1, 1024, 0, stream>>>(deg, N, E, row_ptr, cursor);
    k_build<<<gE, BLK, 0, stream>>>(ei, E, flags, cursor, sdst);

    k_prop<<<gW, BLK, 0, stream>>>(x, dinv, row_ptr, sdst, N, T1);
    k_dense1<<<gW, BLK, 0, stream>>>(x, T1, dinv, row_ptr, sdst, W1, b1, N, Hb);

    k_prop<<<gW, BLK, 0, stream>>>(Hb, dinv, row_ptr, sdst, N, T1);
    k_dense2<<<gW, BLK, 0, stream>>>(Hb, T1, dinv, row_ptr, sdst, W2, b2, N, out);
}

// Round 7
// 794.955 us; speedup vs baseline: 1.6275x; 1.2601x over previous
//
#include <hip/hip_runtime.h>

// ChebNet K=3 on 100K nodes / 1.6M edges, f32 I/O.
// Round 6 fix: replace 232-us single-block scan with 3-phase parallel scan.

static constexpr int BLK = 256;
static constexpr int SCAN_CHUNK = 256;  // elements per block in scan phases

__device__ __forceinline__ unsigned rotl32(unsigned x, int r) {
    return (x << r) | (x >> (32 - r));
}

// JAX partitionable threefry word for element i:
// (b1,b2) = threefry2x32(key=(0,42), counter=(0,i)); word = b1 ^ b2.
__device__ __forceinline__ unsigned tf_word(unsigned i) {
    const unsigned ks0 = 0u;
    const unsigned ks1 = 42u;
    const unsigned ks2 = 0u ^ 42u ^ 0x1BD11BDAu;
    unsigned x0 = 0u + ks0;
    unsigned x1 = i + ks1;
#define TF_RND(r) { x0 += x1; x1 = rotl32(x1, (r)); x1 ^= x0; }
    TF_RND(13) TF_RND(15) TF_RND(26) TF_RND(6)
    x0 += ks1; x1 += ks2 + 1u;
    TF_RND(17) TF_RND(29) TF_RND(16) TF_RND(24)
    x0 += ks2; x1 += ks0 + 2u;
    TF_RND(13) TF_RND(15) TF_RND(26) TF_RND(6)
    x0 += ks0; x1 += ks1 + 3u;
    TF_RND(17) TF_RND(29) TF_RND(16) TF_RND(24)
    x0 += ks1; x1 += ks2 + 4u;
    TF_RND(13) TF_RND(15) TF_RND(26) TF_RND(6)
    x0 += ks2; x1 += ks0 + 5u;
#undef TF_RND
    return x0 ^ x1;
}

__global__ void k_detect(const int* __restrict__ ei, int* __restrict__ flags) {
    __shared__ int cnt_nz;
    int t = threadIdx.x;
    if (t == 0) cnt_nz = 0;
    __syncthreads();
    if (ei[2 * t + 1] != 0) atomicAdd(&cnt_nz, 1);
    __syncthreads();
    if (t == 0) flags[0] = (cnt_nz == 0) ? 1 : 0;
}

__global__ void k_hist(const int* __restrict__ ei, int E,
                       const int* __restrict__ flags, int* __restrict__ deg) {
    int e = blockIdx.x * blockDim.x + threadIdx.x;
    if (e >= E) return;
    int r = flags[0] ? ei[2 * e] : ei[e];
    atomicAdd(&deg[r], 1);
}

__global__ void k_dinv(const int* __restrict__ deg, int N, float* __restrict__ dinv) {
    int v = blockIdx.x * blockDim.x + threadIdx.x;
    if (v < N) {
        int d = deg[v];
        dinv[v] = (d > 0) ? (1.0f / sqrtf((float)d)) : 0.0f;
    }
}

// ---- 3-phase scan: deg[N] -> row_ptr[N+1] (exclusive) + cursor copy ----

// Phase A: per-block sums.
__global__ void k_scanA(const int* __restrict__ deg, int N, int* __restrict__ blk_sum) {
    __shared__ int lds[SCAN_CHUNK];
    int i = blockIdx.x * SCAN_CHUNK + threadIdx.x;
    int v = (i < N) ? deg[i] : 0;
    lds[threadIdx.x] = v;
    __syncthreads();
    for (int off = SCAN_CHUNK / 2; off > 0; off >>= 1) {
        if (threadIdx.x < off) lds[threadIdx.x] += lds[threadIdx.x + off];
        __syncthreads();
    }
    if (threadIdx.x == 0) blk_sum[blockIdx.x] = lds[0];
}

// Phase B: single block, exclusive scan of blk_sum[nb] (nb <= 1024) in LDS.
__global__ void k_scanB(int* __restrict__ blk_sum, int nb) {
    __shared__ int lds[1024];
    int t = threadIdx.x;
    int v = (t < nb) ? blk_sum[t] : 0;
    lds[t] = v;
    __syncthreads();
    for (int off = 1; off < 1024; off <<= 1) {
        int val = (t >= off) ? lds[t - off] : 0;
        __syncthreads();
        lds[t] += val;
        __syncthreads();
    }
    if (t < nb) blk_sum[t] = lds[t] - v;  // exclusive
}

// Phase C: per-block exclusive scan + block offset -> row_ptr & cursor.
__global__ void k_scanC(const int* __restrict__ deg, int N, int E,
                        const int* __restrict__ blk_sum,
                        int* __restrict__ row_ptr, int* __restrict__ cursor) {
    __shared__ int lds[SCAN_CHUNK];
    int t = threadIdx.x;
    int i = blockIdx.x * SCAN_CHUNK + t;
    int v = (i < N) ? deg[i] : 0;
    lds[t] = v;
    __syncthreads();
    for (int off = 1; off < SCAN_CHUNK; off <<= 1) {
        int val = (t >= off) ? lds[t - off] : 0;
        __syncthreads();
        lds[t] += val;
        __syncthreads();
    }
    if (i <= N) {
        int excl = blk_sum[blockIdx.x] + lds[t] - v;
        if (i < N) {
            row_ptr[i] = excl;
            cursor[i] = excl;
        }
    }
    if (i == N - 1 || (blockIdx.x == gridDim.x - 1 && t == SCAN_CHUNK - 1)) {
        row_ptr[N] = E;
    }
}

__global__ void k_build(const int* __restrict__ ei, int E,
                        const int* __restrict__ flags, int* __restrict__ cursor,
                        int* __restrict__ sdst) {
    int e = blockIdx.x * blockDim.x + threadIdx.x;
    if (e >= E) return;
    int r, c;
    if (flags[0]) { r = ei[2 * e]; c = ei[2 * (E + e)]; }
    else          { r = ei[e];     c = ei[E + e]; }
    int p = atomicAdd(&cursor[r], 1);
    sdst[p] = c;
}

// Unrolled gather core: sum_e dinv[c_e]*src[c_e*64+f] over [beg,end).
__device__ __forceinline__ float gather_row(const float* __restrict__ src,
                                            const float* __restrict__ dinv,
                                            const int* __restrict__ sdst,
                                            int beg, int end, int f) {
    float a0 = 0.0f, a1 = 0.0f, a2 = 0.0f, a3 = 0.0f;
    int e = beg;
    int n4 = beg + ((end - beg) & ~3);
    for (; e < n4; e += 4) {
        int c0 = sdst[e + 0];
        int c1 = sdst[e + 1];
        int c2 = sdst[e + 2];
        int c3 = sdst[e + 3];
        float w0 = dinv[c0], w1 = dinv[c1], w2 = dinv[c2], w3 = dinv[c3];
        float v0 = src[(size_t)c0 * 64 + f];
        float v1 = src[(size_t)c1 * 64 + f];
        float v2 = src[(size_t)c2 * 64 + f];
        float v3 = src[(size_t)c3 * 64 + f];
        a0 = fmaf(w0, v0, a0);
        a1 = fmaf(w1, v1, a1);
        a2 = fmaf(w2, v2, a2);
        a3 = fmaf(w3, v3, a3);
    }
    for (; e < end; ++e) {
        int c = sdst[e];
        a0 = fmaf(dinv[c], src[(size_t)c * 64 + f], a0);
    }
    return (a0 + a1) + (a2 + a3);
}

__global__ void __launch_bounds__(BLK) k_prop(const float* __restrict__ src,
                                              const float* __restrict__ dinv,
                                              const int* __restrict__ row_ptr,
                                              const int* __restrict__ sdst,
                                              int N, float* __restrict__ dst) {
    int v = blockIdx.x * (BLK >> 6) + (threadIdx.x >> 6);
    int f = threadIdx.x & 63;
    if (v >= N) return;
    float acc = gather_row(src, dinv, sdst, row_ptr[v], row_ptr[v + 1], f);
    dst[(size_t)v * 64 + f] = -dinv[v] * acc;
}

// Layer 1 fused: Tx2 = 2*prop(T1)-x computed in-kernel.
__global__ void __launch_bounds__(BLK) k_dense1(const float* __restrict__ x,
                                                const float* __restrict__ T1,
                                                const float* __restrict__ dinv,
                                                const int* __restrict__ row_ptr,
                                                const int* __restrict__ sdst,
                                                const float* __restrict__ W1,
                                                const float* __restrict__ b1,
                                                int N, float* __restrict__ H) {
    __shared__ float s0[BLK], s1[BLK], s2[BLK];
    int tid = threadIdx.x;
    int wid = tid >> 6;
    int j = tid & 63;
    int v = blockIdx.x * 4 + wid;
    if (v > N - 1) v = N - 1;
    size_t base = (size_t)v * 64;
    float xv = x[base + j];
    s0[tid] = xv;
    s1[tid] = T1[base + j];
    float acc = gather_row(T1, dinv, sdst, row_ptr[v], row_ptr[v + 1], j);
    s2[tid] = fmaf(-2.0f * dinv[v], acc, -xv);  // tx2
    __syncthreads();
    const float* a0 = &s0[wid * 64];
    const float* a1 = &s1[wid * 64];
    const float* a2 = &s2[wid * 64];
    float o = b1[j];
#pragma unroll 8
    for (int k = 0; k < 64; ++k) {
        o = fmaf(a0[k], W1[k * 64 + j], o);
        o = fmaf(a1[k], W1[4096 + k * 64 + j], o);
        o = fmaf(a2[k], W1[8192 + k * 64 + j], o);
    }
    o = fmaxf(o, 0.0f);
    unsigned bits = tf_word((unsigned)v * 64u + (unsigned)j);
    H[base + j] = (bits & 0x80000000u) ? 0.0f : o * 2.0f;
}

// Layer 2 fused: Tx2' = 2*prop(T1')-H; out = log_softmax(...).
__global__ void __launch_bounds__(BLK) k_dense2(const float* __restrict__ H,
                                                const float* __restrict__ T1,
                                                const float* __restrict__ dinv,
                                                const int* __restrict__ row_ptr,
                                                const int* __restrict__ sdst,
                                                const float* __restrict__ W2,
                                                const float* __restrict__ b2,
                                                int N, float* __restrict__ out) {
    __shared__ float s0[BLK], s1[BLK], s2[BLK];
    int tid = threadIdx.x;
    int wid = tid >> 6;
    int j = tid & 63;
    int v = blockIdx.x * 4 + wid;
    if (v > N - 1) v = N - 1;
    size_t base = (size_t)v * 64;
    float hv = H[base + j];
    s0[tid] = hv;
    s1[tid] = T1[base + j];
    float acc = gather_row(T1, dinv, sdst, row_ptr[v], row_ptr[v + 1], j);
    s2[tid] = fmaf(-2.0f * dinv[v], acc, -hv);
    __syncthreads();
    const float* a0 = &s0[wid * 64];
    const float* a1 = &s1[wid * 64];
    const float* a2 = &s2[wid * 64];
    int jc = j & 31;
    float o = b2[jc];
#pragma unroll 8
    for (int k = 0; k < 64; ++k) {
        o = fmaf(a0[k], W2[k * 32 + jc], o);
        o = fmaf(a1[k], W2[2048 + k * 32 + jc], o);
        o = fmaf(a2[k], W2[4096 + k * 32 + jc], o);
    }
    float m = o;
    for (int d = 16; d >= 1; d >>= 1) m = fmaxf(m, __shfl_xor(m, d));
    float e = expf(o - m);
    float s = e;
    for (int d = 16; d >= 1; d >>= 1) s += __shfl_xor(s, d);
    float r = o - m - logf(s);
    if (j < 32) out[(size_t)v * 32 + jc] = r;
}

extern "C" void kernel_launch(void* const* d_in, const int* in_sizes, int n_in,
                              void* d_out, int out_size, void* d_ws, size_t ws_size,
                              hipStream_t stream) {
    const float* x  = (const float*)d_in[0];
    const int* ei   = (const int*)d_in[1];
    const float* W1 = (const float*)d_in[2];
    const float* b1 = (const float*)d_in[3];
    const float* W2 = (const float*)d_in[4];
    const float* b2 = (const float*)d_in[5];
    float* out = (float*)d_out;

    const int N = in_sizes[0] / 64;
    const int E = in_sizes[1] / 2;

    char* ws = (char*)d_ws;
    size_t off = 0;
    auto alloc = [&](size_t bytes) -> void* {
        void* p = ws + off;
        off = (off + bytes + 511) & ~(size_t)511;
        return p;
    };
    int*   flags   = (int*)alloc(16);
    int*   deg     = (int*)alloc((size_t)N * 4);
    float* dinv    = (float*)alloc((size_t)N * 4);
    int*   row_ptr = (int*)alloc(((size_t)N + 1) * 4);
    int*   cursor  = (int*)alloc((size_t)N * 4);
    int*   blk_sum = (int*)alloc(4096);
    int*   sdst    = (int*)alloc((size_t)E * 4);
    float* T1      = (float*)alloc((size_t)N * 64 * 4);
    float* Hb      = (float*)alloc((size_t)N * 64 * 4);

    hipMemsetAsync(deg, 0, (size_t)N * 4, stream);

    const int gE = (E + BLK - 1) / BLK;
    const int gN = (N + BLK - 1) / BLK;
    const int gW = (N + 3) / 4;
    const int nb = (N + SCAN_CHUNK - 1) / SCAN_CHUNK;  // <= 1024 for N <= 262144

    k_detect<<<1, 256, 0, stream>>>(ei, flags);
    k_hist<<<gE, BLK, 0, stream>>>(ei, E, flags, deg);
    k_dinv<<<gN, BLK, 0, stream>>>(deg, N, dinv);
    k_scanA<<<nb, SCAN_CHUNK, 0, stream>>>(deg, N, blk_sum);
    k_scanB<<<1, 1024, 0, stream>>>(blk_sum, nb);
    k_scanC<<<nb, SCAN_CHUNK, 0, stream>>>(deg, N, E, blk_sum, row_ptr, cursor);
    k_build<<<gE, BLK, 0, stream>>>(ei, E, flags, cursor, sdst);

    k_prop<<<gW, BLK, 0, stream>>>(x, dinv, row_ptr, sdst, N, T1);
    k_dense1<<<gW, BLK, 0, stream>>>(x, T1, dinv, row_ptr, sdst, W1, b1, N, Hb);

    k_prop<<<gW, BLK, 0, stream>>>(Hb, dinv, row_ptr, sdst, N, T1);
    k_dense2<<<gW, BLK, 0, stream>>>(Hb, T1, dinv, row_ptr, sdst, W2, b2, N, out);
}

// Round 8
// 759.067 us; speedup vs baseline: 1.7044x; 1.0473x over previous
//
#include <hip/hip_runtime.h>

// ChebNet K=3 on 100K nodes / 1.6M edges, f32 I/O.
// Round 7: float4 lane-split gather — 4 lane-groups x 16 lanes, each lane
// loads 16B of a row; 4x fewer VMEM/VALU ops per edge vs scalar gather.

static constexpr int BLK = 256;
static constexpr int SCAN_CHUNK = 256;

__device__ __forceinline__ unsigned rotl32(unsigned x, int r) {
    return (x << r) | (x >> (32 - r));
}

// JAX partitionable threefry word for element i:
// (b1,b2) = threefry2x32(key=(0,42), counter=(0,i)); word = b1 ^ b2.
__device__ __forceinline__ unsigned tf_word(unsigned i) {
    const unsigned ks0 = 0u;
    const unsigned ks1 = 42u;
    const unsigned ks2 = 0u ^ 42u ^ 0x1BD11BDAu;
    unsigned x0 = 0u + ks0;
    unsigned x1 = i + ks1;
#define TF_RND(r) { x0 += x1; x1 = rotl32(x1, (r)); x1 ^= x0; }
    TF_RND(13) TF_RND(15) TF_RND(26) TF_RND(6)
    x0 += ks1; x1 += ks2 + 1u;
    TF_RND(17) TF_RND(29) TF_RND(16) TF_RND(24)
    x0 += ks2; x1 += ks0 + 2u;
    TF_RND(13) TF_RND(15) TF_RND(26) TF_RND(6)
    x0 += ks0; x1 += ks1 + 3u;
    TF_RND(17) TF_RND(29) TF_RND(16) TF_RND(24)
    x0 += ks1; x1 += ks2 + 4u;
    TF_RND(13) TF_RND(15) TF_RND(26) TF_RND(6)
    x0 += ks2; x1 += ks0 + 5u;
#undef TF_RND
    return x0 ^ x1;
}

__global__ void k_detect(const int* __restrict__ ei, int* __restrict__ flags) {
    __shared__ int cnt_nz;
    int t = threadIdx.x;
    if (t == 0) cnt_nz = 0;
    __syncthreads();
    if (ei[2 * t + 1] != 0) atomicAdd(&cnt_nz, 1);
    __syncthreads();
    if (t == 0) flags[0] = (cnt_nz == 0) ? 1 : 0;
}

__global__ void k_hist(const int* __restrict__ ei, int E,
                       const int* __restrict__ flags, int* __restrict__ deg) {
    int e = blockIdx.x * blockDim.x + threadIdx.x;
    if (e >= E) return;
    int r = flags[0] ? ei[2 * e] : ei[e];
    atomicAdd(&deg[r], 1);
}

__global__ void k_dinv(const int* __restrict__ deg, int N, float* __restrict__ dinv) {
    int v = blockIdx.x * blockDim.x + threadIdx.x;
    if (v < N) {
        int d = deg[v];
        dinv[v] = (d > 0) ? (1.0f / sqrtf((float)d)) : 0.0f;
    }
}

// ---- 3-phase scan: deg[N] -> row_ptr[N+1] (exclusive) + cursor copy ----
__global__ void k_scanA(const int* __restrict__ deg, int N, int* __restrict__ blk_sum) {
    __shared__ int lds[SCAN_CHUNK];
    int i = blockIdx.x * SCAN_CHUNK + threadIdx.x;
    int v = (i < N) ? deg[i] : 0;
    lds[threadIdx.x] = v;
    __syncthreads();
    for (int off = SCAN_CHUNK / 2; off > 0; off >>= 1) {
        if (threadIdx.x < off) lds[threadIdx.x] += lds[threadIdx.x + off];
        __syncthreads();
    }
    if (threadIdx.x == 0) blk_sum[blockIdx.x] = lds[0];
}

__global__ void k_scanB(int* __restrict__ blk_sum, int nb) {
    __shared__ int lds[1024];
    int t = threadIdx.x;
    int v = (t < nb) ? blk_sum[t] : 0;
    lds[t] = v;
    __syncthreads();
    for (int off = 1; off < 1024; off <<= 1) {
        int val = (t >= off) ? lds[t - off] : 0;
        __syncthreads();
        lds[t] += val;
        __syncthreads();
    }
    if (t < nb) blk_sum[t] = lds[t] - v;  // exclusive
}

__global__ void k_scanC(const int* __restrict__ deg, int N, int E,
                        const int* __restrict__ blk_sum,
                        int* __restrict__ row_ptr, int* __restrict__ cursor) {
    __shared__ int lds[SCAN_CHUNK];
    int t = threadIdx.x;
    int i = blockIdx.x * SCAN_CHUNK + t;
    int v = (i < N) ? deg[i] : 0;
    lds[t] = v;
    __syncthreads();
    for (int off = 1; off < SCAN_CHUNK; off <<= 1) {
        int val = (t >= off) ? lds[t - off] : 0;
        __syncthreads();
        lds[t] += val;
        __syncthreads();
    }
    if (i < N) {
        int excl = blk_sum[blockIdx.x] + lds[t] - v;
        row_ptr[i] = excl;
        cursor[i] = excl;
    }
    if (blockIdx.x == gridDim.x - 1 && t == SCAN_CHUNK - 1) row_ptr[N] = E;
}

__global__ void k_build(const int* __restrict__ ei, int E,
                        const int* __restrict__ flags, int* __restrict__ cursor,
                        int* __restrict__ sdst) {
    int e = blockIdx.x * blockDim.x + threadIdx.x;
    if (e >= E) return;
    int r, c;
    if (flags[0]) { r = ei[2 * e]; c = ei[2 * (E + e)]; }
    else          { r = ei[e];     c = ei[E + e]; }
    int p = atomicAdd(&cursor[r], 1);
    sdst[p] = c;
}

// float4 lane-split gather: grp = lane>>4 handles edges beg+grp, +4, +8, ...;
// each lane loads features [4*fl, 4*fl+4). After xor-shuffle reduce, ALL lanes
// hold the full row sum for their fl.
__device__ __forceinline__ float4 gather4(const float* __restrict__ src,
                                          const float* __restrict__ dinv,
                                          const int* __restrict__ sdst,
                                          int beg, int end, int grp, int fl) {
    float ax0 = 0, ay0 = 0, az0 = 0, aw0 = 0;
    float ax1 = 0, ay1 = 0, az1 = 0, aw1 = 0;
    int e = beg + grp;
    for (; e + 4 < end; e += 8) {
        int c0 = sdst[e];
        int c1 = sdst[e + 4];
        float w0 = dinv[c0], w1 = dinv[c1];
        float4 r0 = *(const float4*)(src + (size_t)c0 * 64 + 4 * fl);
        float4 r1 = *(const float4*)(src + (size_t)c1 * 64 + 4 * fl);
        ax0 = fmaf(w0, r0.x, ax0); ay0 = fmaf(w0, r0.y, ay0);
        az0 = fmaf(w0, r0.z, az0); aw0 = fmaf(w0, r0.w, aw0);
        ax1 = fmaf(w1, r1.x, ax1); ay1 = fmaf(w1, r1.y, ay1);
        az1 = fmaf(w1, r1.z, az1); aw1 = fmaf(w1, r1.w, aw1);
    }
    if (e < end) {
        int c = sdst[e];
        float w = dinv[c];
        float4 r = *(const float4*)(src + (size_t)c * 64 + 4 * fl);
        ax0 = fmaf(w, r.x, ax0); ay0 = fmaf(w, r.y, ay0);
        az0 = fmaf(w, r.z, az0); aw0 = fmaf(w, r.w, aw0);
    }
    float4 a;
    a.x = ax0 + ax1; a.y = ay0 + ay1; a.z = az0 + az1; a.w = aw0 + aw1;
    a.x += __shfl_xor(a.x, 16); a.y += __shfl_xor(a.y, 16);
    a.z += __shfl_xor(a.z, 16); a.w += __shfl_xor(a.w, 16);
    a.x += __shfl_xor(a.x, 32); a.y += __shfl_xor(a.y, 32);
    a.z += __shfl_xor(a.z, 32); a.w += __shfl_xor(a.w, 32);
    return a;
}

__global__ void __launch_bounds__(BLK) k_prop(const float* __restrict__ src,
                                              const float* __restrict__ dinv,
                                              const int* __restrict__ row_ptr,
                                              const int* __restrict__ sdst,
                                              int N, float* __restrict__ dst) {
    int v = blockIdx.x * (BLK >> 6) + (threadIdx.x >> 6);
    if (v >= N) return;
    int lane = threadIdx.x & 63;
    int grp = lane >> 4, fl = lane & 15;
    float4 g = gather4(src, dinv, sdst, row_ptr[v], row_ptr[v + 1], grp, fl);
    if (grp == 0) {
        float dv = -dinv[v];
        float4 o;
        o.x = dv * g.x; o.y = dv * g.y; o.z = dv * g.z; o.w = dv * g.w;
        *(float4*)(dst + (size_t)v * 64 + 4 * fl) = o;
    }
}

// Layer 1 fused: tx2 = 2*prop(T1)-x computed in-kernel; H = dropout(relu(...)).
__global__ void __launch_bounds__(BLK) k_dense1(const float* __restrict__ x,
                                                const float* __restrict__ T1,
                                                const float* __restrict__ dinv,
                                                const int* __restrict__ row_ptr,
                                                const int* __restrict__ sdst,
                                                const float* __restrict__ W1,
                                                const float* __restrict__ b1,
                                                int N, float* __restrict__ H) {
    __shared__ float s0[BLK], s1[BLK], s2[BLK];
    int tid = threadIdx.x;
    int wid = tid >> 6;
    int j = tid & 63;
    int grp = j >> 4, fl = j & 15;
    int v = blockIdx.x * 4 + wid;
    if (v > N - 1) v = N - 1;
    size_t base = (size_t)v * 64;
    s0[tid] = x[base + j];
    s1[tid] = T1[base + j];
    float4 g = gather4(T1, dinv, sdst, row_ptr[v], row_ptr[v + 1], grp, fl);
    if (grp == 0) {
        float dv = -2.0f * dinv[v];
        float4 xq = *(const float4*)(x + base + 4 * fl);
        float4 t;
        t.x = fmaf(dv, g.x, -xq.x); t.y = fmaf(dv, g.y, -xq.y);
        t.z = fmaf(dv, g.z, -xq.z); t.w = fmaf(dv, g.w, -xq.w);
        *(float4*)&s2[wid * 64 + 4 * fl] = t;
    }
    __syncthreads();
    const float* a0 = &s0[wid * 64];
    const float* a1 = &s1[wid * 64];
    const float* a2 = &s2[wid * 64];
    float o = b1[j];
#pragma unroll 8
    for (int k = 0; k < 64; ++k) {
        o = fmaf(a0[k], W1[k * 64 + j], o);
        o = fmaf(a1[k], W1[4096 + k * 64 + j], o);
        o = fmaf(a2[k], W1[8192 + k * 64 + j], o);
    }
    o = fmaxf(o, 0.0f);
    unsigned bits = tf_word((unsigned)v * 64u + (unsigned)j);
    H[base + j] = (bits & 0x80000000u) ? 0.0f : o * 2.0f;
}

// Layer 2 fused: tx2' = 2*prop(T1')-H; out = log_softmax(...).
__global__ void __launch_bounds__(BLK) k_dense2(const float* __restrict__ H,
                                                const float* __restrict__ T1,
                                                const float* __restrict__ dinv,
                                                const int* __restrict__ row_ptr,
                                                const int* __restrict__ sdst,
                                                const float* __restrict__ W2,
                                                const float* __restrict__ b2,
                                                int N, float* __restrict__ out) {
    __shared__ float s0[BLK], s1[BLK], s2[BLK];
    int tid = threadIdx.x;
    int wid = tid >> 6;
    int j = tid & 63;
    int grp = j >> 4, fl = j & 15;
    int v = blockIdx.x * 4 + wid;
    if (v > N - 1) v = N - 1;
    size_t base = (size_t)v * 64;
    s0[tid] = H[base + j];
    s1[tid] = T1[base + j];
    float4 g = gather4(T1, dinv, sdst, row_ptr[v], row_ptr[v + 1], grp, fl);
    if (grp == 0) {
        float dv = -2.0f * dinv[v];
        float4 hq = *(const float4*)(H + base + 4 * fl);
        float4 t;
        t.x = fmaf(dv, g.x, -hq.x); t.y = fmaf(dv, g.y, -hq.y);
        t.z = fmaf(dv, g.z, -hq.z); t.w = fmaf(dv, g.w, -hq.w);
        *(float4*)&s2[wid * 64 + 4 * fl] = t;
    }
    __syncthreads();
    const float* a0 = &s0[wid * 64];
    const float* a1 = &s1[wid * 64];
    const float* a2 = &s2[wid * 64];
    int jc = j & 31;
    float o = b2[jc];
#pragma unroll 8
    for (int k = 0; k < 64; ++k) {
        o = fmaf(a0[k], W2[k * 32 + jc], o);
        o = fmaf(a1[k], W2[2048 + k * 32 + jc], o);
        o = fmaf(a2[k], W2[4096 + k * 32 + jc], o);
    }
    float m = o;
    for (int d = 16; d >= 1; d >>= 1) m = fmaxf(m, __shfl_xor(m, d));
    float e = expf(o - m);
    float s = e;
    for (int d = 16; d >= 1; d >>= 1) s += __shfl_xor(s, d);
    float r = o - m - logf(s);
    if (j < 32) out[(size_t)v * 32 + jc] = r;
}

extern "C" void kernel_launch(void* const* d_in, const int* in_sizes, int n_in,
                              void* d_out, int out_size, void* d_ws, size_t ws_size,
                              hipStream_t stream) {
    const float* x  = (const float*)d_in[0];
    const int* ei   = (const int*)d_in[1];
    const float* W1 = (const float*)d_in[2];
    const float* b1 = (const float*)d_in[3];
    const float* W2 = (const float*)d_in[4];
    const float* b2 = (const float*)d_in[5];
    float* out = (float*)d_out;

    const int N = in_sizes[0] / 64;
    const int E = in_sizes[1] / 2;

    char* ws = (char*)d_ws;
    size_t off = 0;
    auto alloc = [&](size_t bytes) -> void* {
        void* p = ws + off;
        off = (off + bytes + 511) & ~(size_t)511;
        return p;
    };
    int*   flags   = (int*)alloc(16);
    int*   deg     = (int*)alloc((size_t)N * 4);
    float* dinv    = (float*)alloc((size_t)N * 4);
    int*   row_ptr = (int*)alloc(((size_t)N + 1) * 4);
    int*   cursor  = (int*)alloc((size_t)N * 4);
    int*   blk_sum = (int*)alloc(4096);
    int*   sdst    = (int*)alloc((size_t)E * 4);
    float* T1      = (float*)alloc((size_t)N * 64 * 4);
    float* Hb      = (float*)alloc((size_t)N * 64 * 4);

    hipMemsetAsync(deg, 0, (size_t)N * 4, stream);

    const int gE = (E + BLK - 1) / BLK;
    const int gN = (N + BLK - 1) / BLK;
    const int gW = (N + 3) / 4;
    const int nb = (N + SCAN_CHUNK - 1) / SCAN_CHUNK;

    k_detect<<<1, 256, 0, stream>>>(ei, flags);
    k_hist<<<gE, BLK, 0, stream>>>(ei, E, flags, deg);
    k_dinv<<<gN, BLK, 0, stream>>>(deg, N, dinv);
    k_scanA<<<nb, SCAN_CHUNK, 0, stream>>>(deg, N, blk_sum);
    k_scanB<<<1, 1024, 0, stream>>>(blk_sum, nb);
    k_scanC<<<nb, SCAN_CHUNK, 0, stream>>>(deg, N, E, blk_sum, row_ptr, cursor);
    k_build<<<gE, BLK, 0, stream>>>(ei, E, flags, cursor, sdst);

    k_prop<<<gW, BLK, 0, stream>>>(x, dinv, row_ptr, sdst, N, T1);
    k_dense1<<<gW, BLK, 0, stream>>>(x, T1, dinv, row_ptr, sdst, W1, b1, N, Hb);

    k_prop<<<gW, BLK, 0, stream>>>(Hb, dinv, row_ptr, sdst, N, T1);
    k_dense2<<<gW, BLK, 0, stream>>>(Hb, T1, dinv, row_ptr, sdst, W2, b2, N, out);
}

// Round 9
// 696.373 us; speedup vs baseline: 1.8579x; 1.0900x over previous
//
#include <hip/hip_runtime.h>

// ChebNet K=3, W-first restructuring:
//   ChebConv(H) = H@(W0-W2) + S·(H@W1 + 2·S·(H@W2)),  S = -D^-1/2 A D^-1/2 gather
// Layer-2 gathers run on 32-wide rows (half the bytes of 64-wide).
// Buffers B,C (N×64 each) aliased across stages; ws ~60 MB.

static constexpr int BLK = 256;
static constexpr int SCAN_CHUNK = 256;

__device__ __forceinline__ unsigned rotl32(unsigned x, int r) {
    return (x << r) | (x >> (32 - r));
}

// JAX partitionable threefry word for element i:
// (b1,b2) = threefry2x32(key=(0,42), counter=(0,i)); word = b1 ^ b2.
__device__ __forceinline__ unsigned tf_word(unsigned i) {
    const unsigned ks0 = 0u;
    const unsigned ks1 = 42u;
    const unsigned ks2 = 0u ^ 42u ^ 0x1BD11BDAu;
    unsigned x0 = 0u + ks0;
    unsigned x1 = i + ks1;
#define TF_RND(r) { x0 += x1; x1 = rotl32(x1, (r)); x1 ^= x0; }
    TF_RND(13) TF_RND(15) TF_RND(26) TF_RND(6)
    x0 += ks1; x1 += ks2 + 1u;
    TF_RND(17) TF_RND(29) TF_RND(16) TF_RND(24)
    x0 += ks2; x1 += ks0 + 2u;
    TF_RND(13) TF_RND(15) TF_RND(26) TF_RND(6)
    x0 += ks0; x1 += ks1 + 3u;
    TF_RND(17) TF_RND(29) TF_RND(16) TF_RND(24)
    x0 += ks1; x1 += ks2 + 4u;
    TF_RND(13) TF_RND(15) TF_RND(26) TF_RND(6)
    x0 += ks2; x1 += ks0 + 5u;
#undef TF_RND
    return x0 ^ x1;
}

__global__ void k_detect(const int* __restrict__ ei, int* __restrict__ flags) {
    __shared__ int cnt_nz;
    int t = threadIdx.x;
    if (t == 0) cnt_nz = 0;
    __syncthreads();
    if (ei[2 * t + 1] != 0) atomicAdd(&cnt_nz, 1);
    __syncthreads();
    if (t == 0) flags[0] = (cnt_nz == 0) ? 1 : 0;
}

__global__ void k_hist(const int* __restrict__ ei, int E,
                       const int* __restrict__ flags, int* __restrict__ deg) {
    int e = blockIdx.x * blockDim.x + threadIdx.x;
    if (e >= E) return;
    int r = flags[0] ? ei[2 * e] : ei[e];
    atomicAdd(&deg[r], 1);
}

__global__ void k_dinv(const int* __restrict__ deg, int N, float* __restrict__ dinv) {
    int v = blockIdx.x * blockDim.x + threadIdx.x;
    if (v < N) {
        int d = deg[v];
        dinv[v] = (d > 0) ? (1.0f / sqrtf((float)d)) : 0.0f;
    }
}

__global__ void k_scanA(const int* __restrict__ deg, int N, int* __restrict__ blk_sum) {
    __shared__ int lds[SCAN_CHUNK];
    int i = blockIdx.x * SCAN_CHUNK + threadIdx.x;
    int v = (i < N) ? deg[i] : 0;
    lds[threadIdx.x] = v;
    __syncthreads();
    for (int off = SCAN_CHUNK / 2; off > 0; off >>= 1) {
        if (threadIdx.x < off) lds[threadIdx.x] += lds[threadIdx.x + off];
        __syncthreads();
    }
    if (threadIdx.x == 0) blk_sum[blockIdx.x] = lds[0];
}

__global__ void k_scanB(int* __restrict__ blk_sum, int nb) {
    __shared__ int lds[1024];
    int t = threadIdx.x;
    int v = (t < nb) ? blk_sum[t] : 0;
    lds[t] = v;
    __syncthreads();
    for (int off = 1; off < 1024; off <<= 1) {
        int val = (t >= off) ? lds[t - off] : 0;
        __syncthreads();
        lds[t] += val;
        __syncthreads();
    }
    if (t < nb) blk_sum[t] = lds[t] - v;
}

__global__ void k_scanC(const int* __restrict__ deg, int N, int E,
                        const int* __restrict__ blk_sum,
                        int* __restrict__ row_ptr, int* __restrict__ cursor) {
    __shared__ int lds[SCAN_CHUNK];
    int t = threadIdx.x;
    int i = blockIdx.x * SCAN_CHUNK + t;
    int v = (i < N) ? deg[i] : 0;
    lds[t] = v;
    __syncthreads();
    for (int off = 1; off < SCAN_CHUNK; off <<= 1) {
        int val = (t >= off) ? lds[t - off] : 0;
        __syncthreads();
        lds[t] += val;
        __syncthreads();
    }
    if (i < N) {
        int excl = blk_sum[blockIdx.x] + lds[t] - v;
        row_ptr[i] = excl;
        cursor[i] = excl;
    }
    if (blockIdx.x == gridDim.x - 1 && t == SCAN_CHUNK - 1) row_ptr[N] = E;
}

__global__ void k_build(const int* __restrict__ ei, int E,
                        const int* __restrict__ flags, int* __restrict__ cursor,
                        int* __restrict__ sdst) {
    int e = blockIdx.x * blockDim.x + threadIdx.x;
    if (e >= E) return;
    int r, c;
    if (flags[0]) { r = ei[2 * e]; c = ei[2 * (E + e)]; }
    else          { r = ei[e];     c = ei[E + e]; }
    int p = atomicAdd(&cursor[r], 1);
    sdst[p] = c;
}

// Wd1 = W1[0]-W1[2] (4096), Wd2 = W2[0]-W2[2] (2048)
__global__ void k_wdiff(const float* __restrict__ W1, const float* __restrict__ W2,
                        float* __restrict__ Wd1, float* __restrict__ Wd2) {
    int i = blockIdx.x * blockDim.x + threadIdx.x;
    if (i < 4096) Wd1[i] = W1[i] - W1[8192 + i];
    else if (i < 6144) { int k = i - 4096; Wd2[k] = W2[k] - W2[4096 + k]; }
}

// Generic lane-split gather: NG groups, 64/NG lanes each, each lane loads a
// float4 at src[c*pitch + 4*fl]. After xor-reduce ALL lanes hold the full sum
// (for their fl): g = sum_e dinv[c_e] * row4(c_e).
template <int NG>
__device__ __forceinline__ float4 gatherT(const float* __restrict__ src, int pitch,
                                          const float* __restrict__ dinv,
                                          const int* __restrict__ sdst,
                                          int beg, int end, int grp, int fl) {
    float ax0 = 0, ay0 = 0, az0 = 0, aw0 = 0;
    float ax1 = 0, ay1 = 0, az1 = 0, aw1 = 0;
    int e = beg + grp;
    for (; e + NG < end; e += 2 * NG) {
        int c0 = sdst[e];
        int c1 = sdst[e + NG];
        float w0 = dinv[c0], w1 = dinv[c1];
        float4 r0 = *(const float4*)(src + (size_t)c0 * pitch + 4 * fl);
        float4 r1 = *(const float4*)(src + (size_t)c1 * pitch + 4 * fl);
        ax0 = fmaf(w0, r0.x, ax0); ay0 = fmaf(w0, r0.y, ay0);
        az0 = fmaf(w0, r0.z, az0); aw0 = fmaf(w0, r0.w, aw0);
        ax1 = fmaf(w1, r1.x, ax1); ay1 = fmaf(w1, r1.y, ay1);
        az1 = fmaf(w1, r1.z, az1); aw1 = fmaf(w1, r1.w, aw1);
    }
    if (e < end) {
        int c = sdst[e];
        float w = dinv[c];
        float4 r = *(const float4*)(src + (size_t)c * pitch + 4 * fl);
        ax0 = fmaf(w, r.x, ax0); ay0 = fmaf(w, r.y, ay0);
        az0 = fmaf(w, r.z, az0); aw0 = fmaf(w, r.w, aw0);
    }
    float4 a;
    a.x = ax0 + ax1; a.y = ay0 + ay1; a.z = az0 + az1; a.w = aw0 + aw1;
#pragma unroll
    for (int m = 64 / NG; m < 64; m <<= 1) {
        a.x += __shfl_xor(a.x, m); a.y += __shfl_xor(a.y, m);
        a.z += __shfl_xor(a.z, m); a.w += __shfl_xor(a.w, m);
    }
    return a;
}

// Dense layer 1: B = x@W1[1], C = x@W1[2]. Wave per node.
__global__ void __launch_bounds__(BLK) k_denseL1(const float* __restrict__ x,
                                                 const float* __restrict__ W1,
                                                 int N, float* __restrict__ B,
                                                 float* __restrict__ C) {
    __shared__ float s0[BLK];
    int tid = threadIdx.x;
    int wid = tid >> 6;
    int j = tid & 63;
    int v = blockIdx.x * 4 + wid;
    if (v > N - 1) v = N - 1;
    size_t base = (size_t)v * 64;
    s0[tid] = x[base + j];
    __syncthreads();
    const float* a = &s0[wid * 64];
    float t1 = 0.0f, t2 = 0.0f;
#pragma unroll 8
    for (int k = 0; k < 64; ++k) {
        float xv = a[k];
        t1 = fmaf(xv, W1[4096 + k * 64 + j], t1);
        t2 = fmaf(xv, W1[8192 + k * 64 + j], t2);
    }
    B[base + j] = t1;
    C[base + j] = t2;
}

// Gather 1: B[v] += 2*S(C)[v] = B[v] - 2*dinv[v]*sum dinv[c]*C[c]  (in place)
__global__ void __launch_bounds__(BLK) k_gath1(const float* __restrict__ C,
                                               float* __restrict__ B,
                                               const float* __restrict__ dinv,
                                               const int* __restrict__ row_ptr,
                                               const int* __restrict__ sdst,
                                               int N) {
    int v = blockIdx.x * 4 + ((threadIdx.x) >> 6);
    if (v >= N) return;
    int lane = threadIdx.x & 63;
    int grp = lane >> 4, fl = lane & 15;
    float4 g = gatherT<4>(C, 64, dinv, sdst, row_ptr[v], row_ptr[v + 1], grp, fl);
    if (grp == 0) {
        float dv = -2.0f * dinv[v];
        float4 q = *(const float4*)(B + (size_t)v * 64 + 4 * fl);
        q.x = fmaf(dv, g.x, q.x); q.y = fmaf(dv, g.y, q.y);
        q.z = fmaf(dv, g.z, q.z); q.w = fmaf(dv, g.w, q.w);
        *(float4*)(B + (size_t)v * 64 + 4 * fl) = q;
    }
}

// Gather 2: H(=C) = dropout(relu(x@Wd1 + b1 + S(B))).  b1 folded here.
__global__ void __launch_bounds__(BLK) k_gath2(const float* __restrict__ x,
                                               const float* __restrict__ B,
                                               float* __restrict__ C,
                                               const float* __restrict__ dinv,
                                               const int* __restrict__ row_ptr,
                                               const int* __restrict__ sdst,
                                               const float* __restrict__ Wd1,
                                               const float* __restrict__ b1,
                                               int N) {
    __shared__ float s0[BLK], s2[BLK];
    int tid = threadIdx.x;
    int wid = tid >> 6;
    int j = tid & 63;
    int grp = j >> 4, fl = j & 15;
    int v = blockIdx.x * 4 + wid;
    if (v > N - 1) v = N - 1;
    size_t base = (size_t)v * 64;
    s0[tid] = x[base + j];
    float4 g = gatherT<4>(B, 64, dinv, sdst, row_ptr[v], row_ptr[v + 1], grp, fl);
    if (grp == 0) *(float4*)&s2[wid * 64 + 4 * fl] = g;
    __syncthreads();
    const float* a = &s0[wid * 64];
    float q0 = b1[j];
#pragma unroll 8
    for (int k = 0; k < 64; ++k) q0 = fmaf(a[k], Wd1[k * 64 + j], q0);
    float o = fmaf(-dinv[v], s2[wid * 64 + j], q0);
    o = fmaxf(o, 0.0f);
    unsigned bits = tf_word((unsigned)v * 64u + (unsigned)j);
    C[base + j] = (bits & 0x80000000u) ? 0.0f : o * 2.0f;
}

// Dense layer 2: from H rows (C), write D0=H@Wd2+b2eff? (b2 folded in gath4),
// D0 = H@Wd2 -> C[v*64+jc], D1 = H@W2[1] -> C[v*64+32+jc], D2 = H@W2[2] -> B[v*32+jc].
// 2 nodes per wave (half-wave per node), 8 nodes per block.
__global__ void __launch_bounds__(BLK) k_denseL2(const float* __restrict__ W2,
                                                 const float* __restrict__ Wd2,
                                                 int N, float* __restrict__ B,
                                                 float* __restrict__ C) {
    __shared__ float s0[512];
    int tid = threadIdx.x;
    int wid = tid >> 6;
    int lane = tid & 63;
    int half = lane >> 5;
    int jc = lane & 31;
    int r = wid * 2 + half;           // 0..7 row slot in block
    int v = blockIdx.x * 8 + r;
    if (v > N - 1) v = N - 1;
    size_t base = (size_t)v * 64;
    s0[r * 64 + jc] = C[base + jc];
    s0[r * 64 + 32 + jc] = C[base + 32 + jc];
    __syncthreads();
    const float* a = &s0[r * 64];
    float t0 = 0.0f, t1 = 0.0f, t2 = 0.0f;
#pragma unroll 8
    for (int k = 0; k < 64; ++k) {
        float hv = a[k];
        t0 = fmaf(hv, Wd2[k * 32 + jc], t0);
        t1 = fmaf(hv, W2[2048 + k * 32 + jc], t1);
        t2 = fmaf(hv, W2[4096 + k * 32 + jc], t2);
    }
    C[base + jc] = t0;
    C[base + 32 + jc] = t1;
    B[(size_t)v * 32 + jc] = t2;
}

// Gather 3: R2 (in C[.+32]) = D1 + 2*S(D2),  D2 rows are B pitch 32.
__global__ void __launch_bounds__(BLK) k_gath3(const float* __restrict__ B,
                                               float* __restrict__ C,
                                               const float* __restrict__ dinv,
                                               const int* __restrict__ row_ptr,
                                               const int* __restrict__ sdst,
                                               int N) {
    int v = blockIdx.x * 4 + ((threadIdx.x) >> 6);
    if (v >= N) return;
    int lane = threadIdx.x & 63;
    int grp = lane >> 3, fl = lane & 7;
    float4 g = gatherT<8>(B, 32, dinv, sdst, row_ptr[v], row_ptr[v + 1], grp, fl);
    if (grp == 0) {
        float dv = -2.0f * dinv[v];
        float* p = C + (size_t)v * 64 + 32 + 4 * fl;
        float4 q = *(const float4*)p;
        q.x = fmaf(dv, g.x, q.x); q.y = fmaf(dv, g.y, q.y);
        q.z = fmaf(dv, g.z, q.z); q.w = fmaf(dv, g.w, q.w);
        *(float4*)p = q;
    }
}

// Gather 4: out = log_softmax(D0 + b2 + S(R2)).  R2 rows at C+32 pitch 64.
__global__ void __launch_bounds__(BLK) k_gath4(const float* __restrict__ C,
                                               const float* __restrict__ dinv,
                                               const int* __restrict__ row_ptr,
                                               const int* __restrict__ sdst,
                                               const float* __restrict__ b2,
                                               int N, float* __restrict__ out) {
    int v = blockIdx.x * 4 + ((threadIdx.x) >> 6);
    if (v >= N) return;
    int lane = threadIdx.x & 63;
    int grp = lane >> 3, fl = lane & 7;
    float4 g = gatherT<8>(C + 32, 64, dinv, sdst, row_ptr[v], row_ptr[v + 1], grp, fl);
    float dv = -dinv[v];
    float4 d0 = *(const float4*)(C + (size_t)v * 64 + 4 * fl);
    float4 bb = *(const float4*)(b2 + 4 * fl);
    float4 o;
    o.x = fmaf(dv, g.x, d0.x + bb.x);
    o.y = fmaf(dv, g.y, d0.y + bb.y);
    o.z = fmaf(dv, g.z, d0.z + bb.z);
    o.w = fmaf(dv, g.w, d0.w + bb.w);
    float m = fmaxf(fmaxf(o.x, o.y), fmaxf(o.z, o.w));
#pragma unroll
    for (int d = 1; d <= 4; d <<= 1) m = fmaxf(m, __shfl_xor(m, d));
    float s = expf(o.x - m) + expf(o.y - m) + expf(o.z - m) + expf(o.w - m);
#pragma unroll
    for (int d = 1; d <= 4; d <<= 1) s += __shfl_xor(s, d);
    float lse = m + logf(s);
    if (grp == 0) {
        float4 r;
        r.x = o.x - lse; r.y = o.y - lse; r.z = o.z - lse; r.w = o.w - lse;
        *(float4*)(out + (size_t)v * 32 + 4 * fl) = r;
    }
}

extern "C" void kernel_launch(void* const* d_in, const int* in_sizes, int n_in,
                              void* d_out, int out_size, void* d_ws, size_t ws_size,
                              hipStream_t stream) {
    const float* x  = (const float*)d_in[0];
    const int* ei   = (const int*)d_in[1];
    const float* W1 = (const float*)d_in[2];
    const float* b1 = (const float*)d_in[3];
    const float* W2 = (const float*)d_in[4];
    const float* b2 = (const float*)d_in[5];
    float* out = (float*)d_out;

    const int N = in_sizes[0] / 64;
    const int E = in_sizes[1] / 2;

    char* ws = (char*)d_ws;
    size_t off = 0;
    auto alloc = [&](size_t bytes) -> void* {
        void* p = ws + off;
        off = (off + bytes + 511) & ~(size_t)511;
        return p;
    };
    int*   flags   = (int*)alloc(16);
    int*   deg     = (int*)alloc((size_t)N * 4);
    float* dinv    = (float*)alloc((size_t)N * 4);
    int*   row_ptr = (int*)alloc(((size_t)N + 1) * 4);
    int*   cursor  = (int*)alloc((size_t)N * 4);
    int*   blk_sum = (int*)alloc(4096);
    int*   sdst    = (int*)alloc((size_t)E * 4);
    float* Wd1     = (float*)alloc(4096 * 4);
    float* Wd2     = (float*)alloc(2048 * 4);
    float* B       = (float*)alloc((size_t)N * 64 * 4);
    float* C       = (float*)alloc((size_t)N * 64 * 4);
    // total ~60 MB

    hipMemsetAsync(deg, 0, (size_t)N * 4, stream);

    const int gE = (E + BLK - 1) / BLK;
    const int gN = (N + BLK - 1) / BLK;
    const int gW4 = (N + 3) / 4;   // 4 nodes/block
    const int gW8 = (N + 7) / 8;   // 8 nodes/block
    const int nb = (N + SCAN_CHUNK - 1) / SCAN_CHUNK;

    k_detect<<<1, 256, 0, stream>>>(ei, flags);
    k_hist<<<gE, BLK, 0, stream>>>(ei, E, flags, deg);
    k_dinv<<<gN, BLK, 0, stream>>>(deg, N, dinv);
    k_scanA<<<nb, SCAN_CHUNK, 0, stream>>>(deg, N, blk_sum);
    k_scanB<<<1, 1024, 0, stream>>>(blk_sum, nb);
    k_scanC<<<nb, SCAN_CHUNK, 0, stream>>>(deg, N, E, blk_sum, row_ptr, cursor);
    k_build<<<gE, BLK, 0, stream>>>(ei, E, flags, cursor, sdst);
    k_wdiff<<<24, 256, 0, stream>>>(W1, W2, Wd1, Wd2);

    // Layer 1: B=x@W1[1], C=x@W1[2]; B += 2*S(C); C = drop(relu(x@Wd1+b1+S(B)))
    k_denseL1<<<gW4, BLK, 0, stream>>>(x, W1, N, B, C);
    k_gath1<<<gW4, BLK, 0, stream>>>(C, B, dinv, row_ptr, sdst, N);
    k_gath2<<<gW4, BLK, 0, stream>>>(x, B, C, dinv, row_ptr, sdst, Wd1, b1, N);

    // Layer 2: D0,D1 in C; D2 in B; R2 = D1+2*S(D2); out = lsm(D0+b2+S(R2))
    k_denseL2<<<gW8, BLK, 0, stream>>>(W2, Wd2, N, B, C);
    k_gath3<<<gW4, BLK, 0, stream>>>(B, C, dinv, row_ptr, sdst, N);
    k_gath4<<<gW4, BLK, 0, stream>>>(C, dinv, row_ptr, sdst, b2, N, out);
}

// Round 10
// 552.055 us; speedup vs baseline: 2.3436x; 1.2614x over previous
//
#include <hip/hip_runtime.h>

// ChebNet K=3, W-first form: ChebConv(H) = H@(W0-W2) + S·(H@W1 + 2·S·(H@W2)).
// Round 9: CSR build via LDS-staged bucket sort (rows>>8 buckets) — kills the
// 102 MB of partial-line HBM writes from the old random scatter + all global
// histogram atomics.

static constexpr int BLK = 256;
static constexpr int SCAN_CHUNK = 256;
static constexpr int ROWB = 256;      // rows per bucket
static constexpr int RB_SHIFT = 8;
static constexpr int BCAP = 6144;     // bucket capacity (mean ~4081, 22 sigma)
static constexpr int CHUNK = 8192;    // edges per k_bin block

__device__ __forceinline__ unsigned rotl32(unsigned x, int r) {
    return (x << r) | (x >> (32 - r));
}

// JAX partitionable threefry word for element i:
// (b1,b2) = threefry2x32(key=(0,42), counter=(0,i)); word = b1 ^ b2.
__device__ __forceinline__ unsigned tf_word(unsigned i) {
    const unsigned ks0 = 0u;
    const unsigned ks1 = 42u;
    const unsigned ks2 = 0u ^ 42u ^ 0x1BD11BDAu;
    unsigned x0 = 0u + ks0;
    unsigned x1 = i + ks1;
#define TF_RND(r) { x0 += x1; x1 = rotl32(x1, (r)); x1 ^= x0; }
    TF_RND(13) TF_RND(15) TF_RND(26) TF_RND(6)
    x0 += ks1; x1 += ks2 + 1u;
    TF_RND(17) TF_RND(29) TF_RND(16) TF_RND(24)
    x0 += ks2; x1 += ks0 + 2u;
    TF_RND(13) TF_RND(15) TF_RND(26) TF_RND(6)
    x0 += ks0; x1 += ks1 + 3u;
    TF_RND(17) TF_RND(29) TF_RND(16) TF_RND(24)
    x0 += ks1; x1 += ks2 + 4u;
    TF_RND(13) TF_RND(15) TF_RND(26) TF_RND(6)
    x0 += ks2; x1 += ks0 + 5u;
#undef TF_RND
    return x0 ^ x1;
}

__global__ void k_detect(const int* __restrict__ ei, int* __restrict__ flags) {
    __shared__ int cnt_nz;
    int t = threadIdx.x;
    if (t == 0) cnt_nz = 0;
    __syncthreads();
    if (ei[2 * t + 1] != 0) atomicAdd(&cnt_nz, 1);
    __syncthreads();
    if (t == 0) flags[0] = (cnt_nz == 0) ? 1 : 0;
}

// Pass 1: bin edges into row-buckets, LDS-staged for coalesced writes.
__global__ void __launch_bounds__(256) k_bin(const int* __restrict__ ei, int E,
                                             const int* __restrict__ flags,
                                             int* __restrict__ bcnt,
                                             unsigned* __restrict__ bdata, int NB) {
    __shared__ unsigned sval[CHUNK];          // 32 KB
    __shared__ unsigned short sbkt[CHUNK];    // 16 KB
    __shared__ int h[512], ex[512], cur[512], basep[512];  // 8 KB
    int t = threadIdx.x;
    int start = blockIdx.x * CHUNK;
    int lim = min(CHUNK, E - start);
    bool i64 = flags[0] != 0;
    h[t] = 0; h[t + 256] = 0;
    __syncthreads();
    unsigned vv[32];
    unsigned short bb_[32];
#pragma unroll
    for (int k = 0; k < 32; ++k) {
        int idx = k * 256 + t;
        int e = start + idx;
        if (idx < lim) {
            int r, c;
            if (i64) { r = ei[2 * e]; c = ei[2 * (E + e)]; }
            else     { r = ei[e];     c = ei[E + e]; }
            int b = r >> RB_SHIFT;
            vv[k] = ((unsigned)(r & (ROWB - 1)) << 17) | (unsigned)c;
            bb_[k] = (unsigned short)b;
            atomicAdd(&h[b], 1);
        } else {
            bb_[k] = 0xFFFF;
        }
    }
    __syncthreads();
    int i0 = t, i1 = t + 256;
    ex[i0] = h[i0]; ex[i1] = h[i1];
    __syncthreads();
    for (int off = 1; off < 512; off <<= 1) {
        int v0 = (i0 >= off) ? ex[i0 - off] : 0;
        int v1 = (i1 >= off) ? ex[i1 - off] : 0;
        __syncthreads();
        ex[i0] += v0; ex[i1] += v1;
        __syncthreads();
    }
    int e0 = ex[i0] - h[i0], e1 = ex[i1] - h[i1];
    __syncthreads();
    ex[i0] = e0; cur[i0] = e0;
    ex[i1] = e1; cur[i1] = e1;
    if (i0 < NB && h[i0] > 0) basep[i0] = atomicAdd(&bcnt[i0], h[i0]);
    if (i1 < NB && h[i1] > 0) basep[i1] = atomicAdd(&bcnt[i1], h[i1]);
    __syncthreads();
#pragma unroll
    for (int k = 0; k < 32; ++k) {
        if (bb_[k] != 0xFFFF) {
            int p = atomicAdd(&cur[bb_[k]], 1);
            sval[p] = vv[k];
            sbkt[p] = bb_[k];
        }
    }
    __syncthreads();
    for (int i = t; i < lim; i += 256) {
        int b = sbkt[i];
        int gpos = basep[b] + (i - ex[b]);
        if (gpos < BCAP) bdata[(size_t)b * BCAP + gpos] = sval[i];
    }
}

// Per-bucket row histogram -> deg (coalesced, no global atomics).
__global__ void __launch_bounds__(256) k_hist2(const unsigned* __restrict__ bdata,
                                               const int* __restrict__ bcnt,
                                               int N, int* __restrict__ deg) {
    __shared__ int h[ROWB];
    int t = threadIdx.x, b = blockIdx.x;
    h[t] = 0;
    __syncthreads();
    int cnt = min(bcnt[b], BCAP);
    for (int i = t; i < cnt; i += 256)
        atomicAdd(&h[bdata[(size_t)b * BCAP + i] >> 17], 1);
    __syncthreads();
    int r = b * ROWB + t;
    if (r < N) deg[r] = h[t];
}

__global__ void k_dinv(const int* __restrict__ deg, int N, float* __restrict__ dinv) {
    int v = blockIdx.x * blockDim.x + threadIdx.x;
    if (v < N) {
        int d = deg[v];
        dinv[v] = (d > 0) ? (1.0f / sqrtf((float)d)) : 0.0f;
    }
}

__global__ void k_scanA(const int* __restrict__ deg, int N, int* __restrict__ blk_sum) {
    __shared__ int lds[SCAN_CHUNK];
    int i = blockIdx.x * SCAN_CHUNK + threadIdx.x;
    int v = (i < N) ? deg[i] : 0;
    lds[threadIdx.x] = v;
    __syncthreads();
    for (int off = SCAN_CHUNK / 2; off > 0; off >>= 1) {
        if (threadIdx.x < off) lds[threadIdx.x] += lds[threadIdx.x + off];
        __syncthreads();
    }
    if (threadIdx.x == 0) blk_sum[blockIdx.x] = lds[0];
}

__global__ void k_scanB(int* __restrict__ blk_sum, int nb) {
    __shared__ int lds[1024];
    int t = threadIdx.x;
    int v = (t < nb) ? blk_sum[t] : 0;
    lds[t] = v;
    __syncthreads();
    for (int off = 1; off < 1024; off <<= 1) {
        int val = (t >= off) ? lds[t - off] : 0;
        __syncthreads();
        lds[t] += val;
        __syncthreads();
    }
    if (t < nb) blk_sum[t] = lds[t] - v;
}

__global__ void k_scanC(const int* __restrict__ deg, int N, int E,
                        const int* __restrict__ blk_sum, int* __restrict__ row_ptr) {
    __shared__ int lds[SCAN_CHUNK];
    int t = threadIdx.x;
    int i = blockIdx.x * SCAN_CHUNK + t;
    int v = (i < N) ? deg[i] : 0;
    lds[t] = v;
    __syncthreads();
    for (int off = 1; off < SCAN_CHUNK; off <<= 1) {
        int val = (t >= off) ? lds[t - off] : 0;
        __syncthreads();
        lds[t] += val;
        __syncthreads();
    }
    if (i < N) row_ptr[i] = blk_sum[blockIdx.x] + lds[t] - v;
    if (blockIdx.x == gridDim.x - 1 && t == SCAN_CHUNK - 1) row_ptr[N] = E;
}

// Pass 2: place bucket edges at final CSR positions via LDS staging;
// write-out is fully contiguous.
__global__ void __launch_bounds__(256) k_place(const unsigned* __restrict__ bdata,
                                               const int* __restrict__ bcnt,
                                               const int* __restrict__ row_ptr,
                                               int N, int* __restrict__ sdst) {
    __shared__ int cur[ROWB];
    __shared__ int staged[BCAP];   // 24 KB
    int t = threadIdx.x, b = blockIdx.x;
    int r0 = b * ROWB;
    int rbase = row_ptr[r0];
    int r = r0 + t;
    cur[t] = (r < N) ? (row_ptr[r] - rbase) : 0;
    __syncthreads();
    int cnt = min(bcnt[b], BCAP);
    for (int i = t; i < cnt; i += 256) {
        unsigned val = bdata[(size_t)b * BCAP + i];
        int p = atomicAdd(&cur[val >> 17], 1);
        staged[p] = (int)(val & 0x1FFFFu);
    }
    __syncthreads();
    for (int i = t; i < cnt; i += 256) sdst[rbase + i] = staged[i];
}

// Wd1 = W1[0]-W1[2], Wd2 = W2[0]-W2[2]
__global__ void k_wdiff(const float* __restrict__ W1, const float* __restrict__ W2,
                        float* __restrict__ Wd1, float* __restrict__ Wd2) {
    int i = blockIdx.x * blockDim.x + threadIdx.x;
    if (i < 4096) Wd1[i] = W1[i] - W1[8192 + i];
    else if (i < 6144) { int k = i - 4096; Wd2[k] = W2[k] - W2[4096 + k]; }
}

// Lane-split gather: NG groups, each lane loads float4 at src[c*pitch+4*fl];
// xor-reduce leaves full row sum in all lanes.
template <int NG>
__device__ __forceinline__ float4 gatherT(const float* __restrict__ src, int pitch,
                                          const float* __restrict__ dinv,
                                          const int* __restrict__ sdst,
                                          int beg, int end, int grp, int fl) {
    float ax0 = 0, ay0 = 0, az0 = 0, aw0 = 0;
    float ax1 = 0, ay1 = 0, az1 = 0, aw1 = 0;
    int e = beg + grp;
    for (; e + NG < end; e += 2 * NG) {
        int c0 = sdst[e];
        int c1 = sdst[e + NG];
        float w0 = dinv[c0], w1 = dinv[c1];
        float4 r0 = *(const float4*)(src + (size_t)c0 * pitch + 4 * fl);
        float4 r1 = *(const float4*)(src + (size_t)c1 * pitch + 4 * fl);
        ax0 = fmaf(w0, r0.x, ax0); ay0 = fmaf(w0, r0.y, ay0);
        az0 = fmaf(w0, r0.z, az0); aw0 = fmaf(w0, r0.w, aw0);
        ax1 = fmaf(w1, r1.x, ax1); ay1 = fmaf(w1, r1.y, ay1);
        az1 = fmaf(w1, r1.z, az1); aw1 = fmaf(w1, r1.w, aw1);
    }
    if (e < end) {
        int c = sdst[e];
        float w = dinv[c];
        float4 r = *(const float4*)(src + (size_t)c * pitch + 4 * fl);
        ax0 = fmaf(w, r.x, ax0); ay0 = fmaf(w, r.y, ay0);
        az0 = fmaf(w, r.z, az0); aw0 = fmaf(w, r.w, aw0);
    }
    float4 a;
    a.x = ax0 + ax1; a.y = ay0 + ay1; a.z = az0 + az1; a.w = aw0 + aw1;
#pragma unroll
    for (int m = 64 / NG; m < 64; m <<= 1) {
        a.x += __shfl_xor(a.x, m); a.y += __shfl_xor(a.y, m);
        a.z += __shfl_xor(a.z, m); a.w += __shfl_xor(a.w, m);
    }
    return a;
}

// Dense layer 1: B = x@W1[1], C = x@W1[2]. Wave per node.
__global__ void __launch_bounds__(BLK) k_denseL1(const float* __restrict__ x,
                                                 const float* __restrict__ W1,
                                                 int N, float* __restrict__ B,
                                                 float* __restrict__ C) {
    __shared__ float s0[BLK];
    int tid = threadIdx.x;
    int wid = tid >> 6;
    int j = tid & 63;
    int v = blockIdx.x * 4 + wid;
    if (v > N - 1) v = N - 1;
    size_t base = (size_t)v * 64;
    s0[tid] = x[base + j];
    __syncthreads();
    const float* a = &s0[wid * 64];
    float t1 = 0.0f, t2 = 0.0f;
#pragma unroll 8
    for (int k = 0; k < 64; ++k) {
        float xv = a[k];
        t1 = fmaf(xv, W1[4096 + k * 64 + j], t1);
        t2 = fmaf(xv, W1[8192 + k * 64 + j], t2);
    }
    B[base + j] = t1;
    C[base + j] = t2;
}

// Gather 1: B[v] -= 2*dinv[v]*sum dinv[c]*C[c]  (in place)
__global__ void __launch_bounds__(BLK) k_gath1(const float* __restrict__ C,
                                               float* __restrict__ B,
                                               const float* __restrict__ dinv,
                                               const int* __restrict__ row_ptr,
                                               const int* __restrict__ sdst,
                                               int N) {
    int v = blockIdx.x * 4 + ((threadIdx.x) >> 6);
    if (v >= N) return;
    int lane = threadIdx.x & 63;
    int grp = lane >> 4, fl = lane & 15;
    float4 g = gatherT<4>(C, 64, dinv, sdst, row_ptr[v], row_ptr[v + 1], grp, fl);
    if (grp == 0) {
        float dv = -2.0f * dinv[v];
        float4 q = *(const float4*)(B + (size_t)v * 64 + 4 * fl);
        q.x = fmaf(dv, g.x, q.x); q.y = fmaf(dv, g.y, q.y);
        q.z = fmaf(dv, g.z, q.z); q.w = fmaf(dv, g.w, q.w);
        *(float4*)(B + (size_t)v * 64 + 4 * fl) = q;
    }
}

// Gather 2: H(=C) = dropout(relu(x@Wd1 + b1 + S(B))).
__global__ void __launch_bounds__(BLK) k_gath2(const float* __restrict__ x,
                                               const float* __restrict__ B,
                                               float* __restrict__ C,
                                               const float* __restrict__ dinv,
                                               const int* __restrict__ row_ptr,
                                               const int* __restrict__ sdst,
                                               const float* __restrict__ Wd1,
                                               const float* __restrict__ b1,
                                               int N) {
    __shared__ float s0[BLK], s2[BLK];
    int tid = threadIdx.x;
    int wid = tid >> 6;
    int j = tid & 63;
    int grp = j >> 4, fl = j & 15;
    int v = blockIdx.x * 4 + wid;
    if (v > N - 1) v = N - 1;
    size_t base = (size_t)v * 64;
    s0[tid] = x[base + j];
    float4 g = gatherT<4>(B, 64, dinv, sdst, row_ptr[v], row_ptr[v + 1], grp, fl);
    if (grp == 0) *(float4*)&s2[wid * 64 + 4 * fl] = g;
    __syncthreads();
    const float* a = &s0[wid * 64];
    float q0 = b1[j];
#pragma unroll 8
    for (int k = 0; k < 64; ++k) q0 = fmaf(a[k], Wd1[k * 64 + j], q0);
    float o = fmaf(-dinv[v], s2[wid * 64 + j], q0);
    o = fmaxf(o, 0.0f);
    unsigned bits = tf_word((unsigned)v * 64u + (unsigned)j);
    C[base + j] = (bits & 0x80000000u) ? 0.0f : o * 2.0f;
}

// Dense layer 2: D0=H@Wd2 -> C[.,0:32]; D1=H@W2[1] -> C[.,32:64]; D2=H@W2[2] -> B pitch 32.
__global__ void __launch_bounds__(BLK) k_denseL2(const float* __restrict__ W2,
                                                 const float* __restrict__ Wd2,
                                                 int N, float* __restrict__ B,
                                                 float* __restrict__ C) {
    __shared__ float s0[512];
    int tid = threadIdx.x;
    int wid = tid >> 6;
    int lane = tid & 63;
    int half = lane >> 5;
    int jc = lane & 31;
    int r = wid * 2 + half;
    int v = blockIdx.x * 8 + r;
    if (v > N - 1) v = N - 1;
    size_t base = (size_t)v * 64;
    s0[r * 64 + jc] = C[base + jc];
    s0[r * 64 + 32 + jc] = C[base + 32 + jc];
    __syncthreads();
    const float* a = &s0[r * 64];
    float t0 = 0.0f, t1 = 0.0f, t2 = 0.0f;
#pragma unroll 8
    for (int k = 0; k < 64; ++k) {
        float hv = a[k];
        t0 = fmaf(hv, Wd2[k * 32 + jc], t0);
        t1 = fmaf(hv, W2[2048 + k * 32 + jc], t1);
        t2 = fmaf(hv, W2[4096 + k * 32 + jc], t2);
    }
    C[base + jc] = t0;
    C[base + 32 + jc] = t1;
    B[(size_t)v * 32 + jc] = t2;
}

// Gather 3: R2 (C[.,32:64]) = D1 + 2*S(D2), D2 rows pitch 32 in B.
__global__ void __launch_bounds__(BLK) k_gath3(const float* __restrict__ B,
                                               float* __restrict__ C,
                                               const float* __restrict__ dinv,
                                               const int* __restrict__ row_ptr,
                                               const int* __restrict__ sdst,
                                               int N) {
    int v = blockIdx.x * 4 + ((threadIdx.x) >> 6);
    if (v >= N) return;
    int lane = threadIdx.x & 63;
    int grp = lane >> 3, fl = lane & 7;
    float4 g = gatherT<8>(B, 32, dinv, sdst, row_ptr[v], row_ptr[v + 1], grp, fl);
    if (grp == 0) {
        float dv = -2.0f * dinv[v];
        float* p = C + (size_t)v * 64 + 32 + 4 * fl;
        float4 q = *(const float4*)p;
        q.x = fmaf(dv, g.x, q.x); q.y = fmaf(dv, g.y, q.y);
        q.z = fmaf(dv, g.z, q.z); q.w = fmaf(dv, g.w, q.w);
        *(float4*)p = q;
    }
}

// Gather 4: out = log_softmax(D0 + b2 + S(R2)).
__global__ void __launch_bounds__(BLK) k_gath4(const float* __restrict__ C,
                                               const float* __restrict__ dinv,
                                               const int* __restrict__ row_ptr,
                                               const int* __restrict__ sdst,
                                               const float* __restrict__ b2,
                                               int N, float* __restrict__ out) {
    int v = blockIdx.x * 4 + ((threadIdx.x) >> 6);
    if (v >= N) return;
    int lane = threadIdx.x & 63;
    int grp = lane >> 3, fl = lane & 7;
    float4 g = gatherT<8>(C + 32, 64, dinv, sdst, row_ptr[v], row_ptr[v + 1], grp, fl);
    float dv = -dinv[v];
    float4 d0 = *(const float4*)(C + (size_t)v * 64 + 4 * fl);
    float4 bb = *(const float4*)(b2 + 4 * fl);
    float4 o;
    o.x = fmaf(dv, g.x, d0.x + bb.x);
    o.y = fmaf(dv, g.y, d0.y + bb.y);
    o.z = fmaf(dv, g.z, d0.z + bb.z);
    o.w = fmaf(dv, g.w, d0.w + bb.w);
    float m = fmaxf(fmaxf(o.x, o.y), fmaxf(o.z, o.w));
#pragma unroll
    for (int d = 1; d <= 4; d <<= 1) m = fmaxf(m, __shfl_xor(m, d));
    float s = expf(o.x - m) + expf(o.y - m) + expf(o.z - m) + expf(o.w - m);
#pragma unroll
    for (int d = 1; d <= 4; d <<= 1) s += __shfl_xor(s, d);
    float lse = m + logf(s);
    if (grp == 0) {
        float4 r;
        r.x = o.x - lse; r.y = o.y - lse; r.z = o.z - lse; r.w = o.w - lse;
        *(float4*)(out + (size_t)v * 32 + 4 * fl) = r;
    }
}

extern "C" void kernel_launch(void* const* d_in, const int* in_sizes, int n_in,
                              void* d_out, int out_size, void* d_ws, size_t ws_size,
                              hipStream_t stream) {
    const float* x  = (const float*)d_in[0];
    const int* ei   = (const int*)d_in[1];
    const float* W1 = (const float*)d_in[2];
    const float* b1 = (const float*)d_in[3];
    const float* W2 = (const float*)d_in[4];
    const float* b2 = (const float*)d_in[5];
    float* out = (float*)d_out;

    const int N = in_sizes[0] / 64;
    const int E = in_sizes[1] / 2;
    const int NB = (N + ROWB - 1) >> RB_SHIFT;

    char* ws = (char*)d_ws;
    size_t off = 0;
    auto alloc = [&](size_t bytes) -> void* {
        void* p = ws + off;
        off = (off + bytes + 511) & ~(size_t)511;
        return p;
    };
    int*      flags   = (int*)alloc(16);
    int*      deg     = (int*)alloc((size_t)N * 4);
    float*    dinv    = (float*)alloc((size_t)N * 4);
    int*      row_ptr = (int*)alloc(((size_t)N + 1) * 4);
    int*      blk_sum = (int*)alloc(4096);
    int*      bcnt    = (int*)alloc((size_t)NB * 4);
    unsigned* bdata   = (unsigned*)alloc((size_t)NB * BCAP * 4);
    int*      sdst    = (int*)alloc((size_t)E * 4);
    float*    Wd1     = (float*)alloc(4096 * 4);
    float*    Wd2     = (float*)alloc(2048 * 4);
    float*    B       = (float*)alloc((size_t)N * 64 * 4);
    float*    C       = (float*)alloc((size_t)N * 64 * 4);
    // total ~69 MB

    hipMemsetAsync(bcnt, 0, (size_t)NB * 4, stream);

    const int gN = (N + BLK - 1) / BLK;
    const int gW4 = (N + 3) / 4;
    const int gW8 = (N + 7) / 8;
    const int nb = (N + SCAN_CHUNK - 1) / SCAN_CHUNK;
    const int gBin = (E + CHUNK - 1) / CHUNK;

    k_detect<<<1, 256, 0, stream>>>(ei, flags);
    k_bin<<<gBin, 256, 0, stream>>>(ei, E, flags, bcnt, bdata, NB);
    k_hist2<<<NB, 256, 0, stream>>>(bdata, bcnt, N, deg);
    k_dinv<<<gN, BLK, 0, stream>>>(deg, N, dinv);
    k_scanA<<<nb, SCAN_CHUNK, 0, stream>>>(deg, N, blk_sum);
    k_scanB<<<1, 1024, 0, stream>>>(blk_sum, nb);
    k_scanC<<<nb, SCAN_CHUNK, 0, stream>>>(deg, N, E, blk_sum, row_ptr);
    k_place<<<NB, 256, 0, stream>>>(bdata, bcnt, row_ptr, N, sdst);
    k_wdiff<<<24, 256, 0, stream>>>(W1, W2, Wd1, Wd2);

    // Layer 1: B=x@W1[1], C=x@W1[2]; B += 2*S(C); C = drop(relu(x@Wd1+b1+S(B)))
    k_denseL1<<<gW4, BLK, 0, stream>>>(x, W1, N, B, C);
    k_gath1<<<gW4, BLK, 0, stream>>>(C, B, dinv, row_ptr, sdst, N);
    k_gath2<<<gW4, BLK, 0, stream>>>(x, B, C, dinv, row_ptr, sdst, Wd1, b1, N);

    // Layer 2: D0,D1 in C; D2 in B; R2 = D1+2*S(D2); out = lsm(D0+b2+S(R2))
    k_denseL2<<<gW8, BLK, 0, stream>>>(W2, Wd2, N, B, C);
    k_gath3<<<gW4, BLK, 0, stream>>>(B, C, dinv, row_ptr, sdst, N);
    k_gath4<<<gW4, BLK, 0, stream>>>(C, dinv, row_ptr, sdst, b2, N, out);
}

// Round 12
// 444.741 us; speedup vs baseline: 2.9091x; 1.2413x over previous
//
#include <hip/hip_runtime.h>

// ChebNet K=3, W-first form: ChebConv(H) = H@(W0-W2) + S·(H@W1 + 2·S·(H@W2)).
// Round 11 fix: k_gath2's dropout-word shuffles moved OUT of the divergent
// `if (grp==0)` branch (inactive-source-lane shuffle was undefined -> wrong
// mask). D buffer aliased over dead bdata region (ws ~85 MB).

static constexpr int BLK = 256;
static constexpr int SCAN_CHUNK = 256;
static constexpr int ROWB = 256;
static constexpr int RB_SHIFT = 8;
static constexpr int BCAP = 6144;
static constexpr int CHUNK = 8192;

__device__ __forceinline__ unsigned rotl32(unsigned x, int r) {
    return (x << r) | (x >> (32 - r));
}

// JAX partitionable threefry word for element i:
// (b1,b2) = threefry2x32(key=(0,42), counter=(0,i)); word = b1 ^ b2.
__device__ __forceinline__ unsigned tf_word(unsigned i) {
    const unsigned ks0 = 0u;
    const unsigned ks1 = 42u;
    const unsigned ks2 = 0u ^ 42u ^ 0x1BD11BDAu;
    unsigned x0 = 0u + ks0;
    unsigned x1 = i + ks1;
#define TF_RND(r) { x0 += x1; x1 = rotl32(x1, (r)); x1 ^= x0; }
    TF_RND(13) TF_RND(15) TF_RND(26) TF_RND(6)
    x0 += ks1; x1 += ks2 + 1u;
    TF_RND(17) TF_RND(29) TF_RND(16) TF_RND(24)
    x0 += ks2; x1 += ks0 + 2u;
    TF_RND(13) TF_RND(15) TF_RND(26) TF_RND(6)
    x0 += ks0; x1 += ks1 + 3u;
    TF_RND(17) TF_RND(29) TF_RND(16) TF_RND(24)
    x0 += ks1; x1 += ks2 + 4u;
    TF_RND(13) TF_RND(15) TF_RND(26) TF_RND(6)
    x0 += ks2; x1 += ks0 + 5u;
#undef TF_RND
    return x0 ^ x1;
}

__global__ void k_detect(const int* __restrict__ ei, int* __restrict__ flags) {
    __shared__ int cnt_nz;
    int t = threadIdx.x;
    if (t == 0) cnt_nz = 0;
    __syncthreads();
    if (ei[2 * t + 1] != 0) atomicAdd(&cnt_nz, 1);
    __syncthreads();
    if (t == 0) flags[0] = (cnt_nz == 0) ? 1 : 0;
}

// Pass 1: bin edges into row-buckets, LDS-staged for coalesced writes.
__global__ void __launch_bounds__(256) k_bin(const int* __restrict__ ei, int E,
                                             const int* __restrict__ flags,
                                             int* __restrict__ bcnt,
                                             unsigned* __restrict__ bdata, int NB) {
    __shared__ unsigned sval[CHUNK];
    __shared__ unsigned short sbkt[CHUNK];
    __shared__ int h[512], ex[512], cur[512], basep[512];
    int t = threadIdx.x;
    int start = blockIdx.x * CHUNK;
    int lim = min(CHUNK, E - start);
    bool i64 = flags[0] != 0;
    h[t] = 0; h[t + 256] = 0;
    __syncthreads();
    unsigned vv[32];
    unsigned short bb_[32];
#pragma unroll
    for (int k = 0; k < 32; ++k) {
        int idx = k * 256 + t;
        int e = start + idx;
        if (idx < lim) {
            int r, c;
            if (i64) { r = ei[2 * e]; c = ei[2 * (E + e)]; }
            else     { r = ei[e];     c = ei[E + e]; }
            int b = r >> RB_SHIFT;
            vv[k] = ((unsigned)(r & (ROWB - 1)) << 17) | (unsigned)c;
            bb_[k] = (unsigned short)b;
            atomicAdd(&h[b], 1);
        } else {
            bb_[k] = 0xFFFF;
        }
    }
    __syncthreads();
    int i0 = t, i1 = t + 256;
    ex[i0] = h[i0]; ex[i1] = h[i1];
    __syncthreads();
    for (int off = 1; off < 512; off <<= 1) {
        int v0 = (i0 >= off) ? ex[i0 - off] : 0;
        int v1 = (i1 >= off) ? ex[i1 - off] : 0;
        __syncthreads();
        ex[i0] += v0; ex[i1] += v1;
        __syncthreads();
    }
    int e0 = ex[i0] - h[i0], e1 = ex[i1] - h[i1];
    __syncthreads();
    ex[i0] = e0; cur[i0] = e0;
    ex[i1] = e1; cur[i1] = e1;
    if (i0 < NB && h[i0] > 0) basep[i0] = atomicAdd(&bcnt[i0], h[i0]);
    if (i1 < NB && h[i1] > 0) basep[i1] = atomicAdd(&bcnt[i1], h[i1]);
    __syncthreads();
#pragma unroll
    for (int k = 0; k < 32; ++k) {
        if (bb_[k] != 0xFFFF) {
            int p = atomicAdd(&cur[bb_[k]], 1);
            sval[p] = vv[k];
            sbkt[p] = bb_[k];
        }
    }
    __syncthreads();
    for (int i = t; i < lim; i += 256) {
        int b = sbkt[i];
        int gpos = basep[b] + (i - ex[b]);
        if (gpos < BCAP) bdata[(size_t)b * BCAP + gpos] = sval[i];
    }
}

__global__ void __launch_bounds__(256) k_hist2(const unsigned* __restrict__ bdata,
                                               const int* __restrict__ bcnt,
                                               int N, int* __restrict__ deg) {
    __shared__ int h[ROWB];
    int t = threadIdx.x, b = blockIdx.x;
    h[t] = 0;
    __syncthreads();
    int cnt = min(bcnt[b], BCAP);
    for (int i = t; i < cnt; i += 256)
        atomicAdd(&h[bdata[(size_t)b * BCAP + i] >> 17], 1);
    __syncthreads();
    int r = b * ROWB + t;
    if (r < N) deg[r] = h[t];
}

__global__ void k_dinv(const int* __restrict__ deg, int N, float* __restrict__ dinv) {
    int v = blockIdx.x * blockDim.x + threadIdx.x;
    if (v < N) {
        int d = deg[v];
        dinv[v] = (d > 0) ? (1.0f / sqrtf((float)d)) : 0.0f;
    }
}

__global__ void k_scanA(const int* __restrict__ deg, int N, int* __restrict__ blk_sum) {
    __shared__ int lds[SCAN_CHUNK];
    int i = blockIdx.x * SCAN_CHUNK + threadIdx.x;
    int v = (i < N) ? deg[i] : 0;
    lds[threadIdx.x] = v;
    __syncthreads();
    for (int off = SCAN_CHUNK / 2; off > 0; off >>= 1) {
        if (threadIdx.x < off) lds[threadIdx.x] += lds[threadIdx.x + off];
        __syncthreads();
    }
    if (threadIdx.x == 0) blk_sum[blockIdx.x] = lds[0];
}

__global__ void k_scanB(int* __restrict__ blk_sum, int nb) {
    __shared__ int lds[1024];
    int t = threadIdx.x;
    int v = (t < nb) ? blk_sum[t] : 0;
    lds[t] = v;
    __syncthreads();
    for (int off = 1; off < 1024; off <<= 1) {
        int val = (t >= off) ? lds[t - off] : 0;
        __syncthreads();
        lds[t] += val;
        __syncthreads();
    }
    if (t < nb) blk_sum[t] = lds[t] - v;
}

__global__ void k_scanC(const int* __restrict__ deg, int N, int E,
                        const int* __restrict__ blk_sum, int* __restrict__ row_ptr) {
    __shared__ int lds[SCAN_CHUNK];
    int t = threadIdx.x;
    int i = blockIdx.x * SCAN_CHUNK + t;
    int v = (i < N) ? deg[i] : 0;
    lds[t] = v;
    __syncthreads();
    for (int off = 1; off < SCAN_CHUNK; off <<= 1) {
        int val = (t >= off) ? lds[t - off] : 0;
        __syncthreads();
        lds[t] += val;
        __syncthreads();
    }
    if (i < N) row_ptr[i] = blk_sum[blockIdx.x] + lds[t] - v;
    if (blockIdx.x == gridDim.x - 1 && t == SCAN_CHUNK - 1) row_ptr[N] = E;
}

__global__ void __launch_bounds__(256) k_place(const unsigned* __restrict__ bdata,
                                               const int* __restrict__ bcnt,
                                               const int* __restrict__ row_ptr,
                                               int N, int* __restrict__ sdst) {
    __shared__ int cur[ROWB];
    __shared__ int staged[BCAP];
    int t = threadIdx.x, b = blockIdx.x;
    int r0 = b * ROWB;
    int rbase = row_ptr[r0];
    int r = r0 + t;
    cur[t] = (r < N) ? (row_ptr[r] - rbase) : 0;
    __syncthreads();
    int cnt = min(bcnt[b], BCAP);
    for (int i = t; i < cnt; i += 256) {
        unsigned val = bdata[(size_t)b * BCAP + i];
        int p = atomicAdd(&cur[val >> 17], 1);
        staged[p] = (int)(val & 0x1FFFFu);
    }
    __syncthreads();
    for (int i = t; i < cnt; i += 256) sdst[rbase + i] = staged[i];
}

// W-stationary dense, layer 1. Block = 32 nodes. LDS: W1[1], W1[2],
// Wd=W1[0]-W1[2] (48 KB) + 32 x-rows (8 KB). Outputs B, C, D(=x@Wd+b1).
__global__ void __launch_bounds__(256) k_dense3(const float* __restrict__ x,
                                                const float* __restrict__ W1,
                                                const float* __restrict__ b1,
                                                int N, float* __restrict__ B,
                                                float* __restrict__ C,
                                                float* __restrict__ D) {
    __shared__ float sW1[4096], sW2[4096], sWd[4096], sx[2048], sb[64];
    int t = threadIdx.x;
    for (int i = t; i < 4096; i += 256) {
        float w0 = W1[i];
        float w2 = W1[8192 + i];
        sW1[i] = W1[4096 + i];
        sW2[i] = w2;
        sWd[i] = w0 - w2;
    }
    if (t < 64) sb[t] = b1[t];
    int v0 = blockIdx.x * 32;
    for (int i = t; i < 2048; i += 256) {
        int m = i >> 6, f = i & 63;
        int v = min(v0 + m, N - 1);
        sx[i] = x[(size_t)v * 64 + f];
    }
    __syncthreads();
    int wid = t >> 6, j = t & 63;
    float a0[8], a1[8], a2[8];
#pragma unroll
    for (int m = 0; m < 8; ++m) { a0[m] = 0.0f; a1[m] = 0.0f; a2[m] = sb[j]; }
    const float* xr = &sx[wid * 512];
#pragma unroll 2
    for (int k = 0; k < 64; ++k) {
        float w1v = sW1[k * 64 + j];
        float w2v = sW2[k * 64 + j];
        float wdv = sWd[k * 64 + j];
#pragma unroll
        for (int m = 0; m < 8; ++m) {
            float xk = xr[m * 64 + k];
            a0[m] = fmaf(xk, w1v, a0[m]);
            a1[m] = fmaf(xk, w2v, a1[m]);
            a2[m] = fmaf(xk, wdv, a2[m]);
        }
    }
#pragma unroll
    for (int m = 0; m < 8; ++m) {
        int v = v0 + wid * 8 + m;
        if (v < N) {
            size_t base = (size_t)v * 64 + j;
            B[base] = a0[m];
            C[base] = a1[m];
            D[base] = a2[m];
        }
    }
}

// W-stationary dense, layer 2. Block = 32 nodes (H rows from C).
// D0=H@(W2[0]-W2[2]) -> C[.,0:32]; D1=H@W2[1] -> C[.,32:64]; D2=H@W2[2] -> B pitch 32.
__global__ void __launch_bounds__(256) k_dense3b(const float* __restrict__ W2,
                                                 int N, float* __restrict__ B,
                                                 float* __restrict__ C) {
    __shared__ float sWd[2048], sW1[2048], sW2[2048], sx[2048];
    int t = threadIdx.x;
    for (int i = t; i < 2048; i += 256) {
        float w0 = W2[i];
        float w2 = W2[4096 + i];
        sWd[i] = w0 - w2;
        sW1[i] = W2[2048 + i];
        sW2[i] = w2;
    }
    int v0 = blockIdx.x * 32;
    for (int i = t; i < 2048; i += 256) {
        int m = i >> 6, f = i & 63;
        int v = min(v0 + m, N - 1);
        sx[i] = C[(size_t)v * 64 + f];
    }
    __syncthreads();
    int wid = t >> 6;
    int lane = t & 63;
    int half = lane >> 5, jc = lane & 31;
    float d0[4], d1[4], d2[4];
#pragma unroll
    for (int m = 0; m < 4; ++m) { d0[m] = 0.0f; d1[m] = 0.0f; d2[m] = 0.0f; }
#pragma unroll 2
    for (int k = 0; k < 64; ++k) {
        float wdv = sWd[k * 32 + jc];
        float w1v = sW1[k * 32 + jc];
        float w2v = sW2[k * 32 + jc];
#pragma unroll
        for (int m = 0; m < 4; ++m) {
            float xk = sx[(wid * 8 + 2 * m + half) * 64 + k];
            d0[m] = fmaf(xk, wdv, d0[m]);
            d1[m] = fmaf(xk, w1v, d1[m]);
            d2[m] = fmaf(xk, w2v, d2[m]);
        }
    }
#pragma unroll
    for (int m = 0; m < 4; ++m) {
        int v = v0 + wid * 8 + 2 * m + half;
        if (v < N) {
            size_t base = (size_t)v * 64;
            C[base + jc] = d0[m];
            C[base + 32 + jc] = d1[m];
            B[(size_t)v * 32 + jc] = d2[m];
        }
    }
}

// Lane-split gather: NG groups, each lane loads float4 at src[c*pitch+4*fl];
// xor-reduce leaves full row sum in all lanes.
template <int NG>
__device__ __forceinline__ float4 gatherT(const float* __restrict__ src, int pitch,
                                          const float* __restrict__ dinv,
                                          const int* __restrict__ sdst,
                                          int beg, int end, int grp, int fl) {
    float ax0 = 0, ay0 = 0, az0 = 0, aw0 = 0;
    float ax1 = 0, ay1 = 0, az1 = 0, aw1 = 0;
    int e = beg + grp;
    for (; e + NG < end; e += 2 * NG) {
        int c0 = sdst[e];
        int c1 = sdst[e + NG];
        float w0 = dinv[c0], w1 = dinv[c1];
        float4 r0 = *(const float4*)(src + (size_t)c0 * pitch + 4 * fl);
        float4 r1 = *(const float4*)(src + (size_t)c1 * pitch + 4 * fl);
        ax0 = fmaf(w0, r0.x, ax0); ay0 = fmaf(w0, r0.y, ay0);
        az0 = fmaf(w0, r0.z, az0); aw0 = fmaf(w0, r0.w, aw0);
        ax1 = fmaf(w1, r1.x, ax1); ay1 = fmaf(w1, r1.y, ay1);
        az1 = fmaf(w1, r1.z, az1); aw1 = fmaf(w1, r1.w, aw1);
    }
    if (e < end) {
        int c = sdst[e];
        float w = dinv[c];
        float4 r = *(const float4*)(src + (size_t)c * pitch + 4 * fl);
        ax0 = fmaf(w, r.x, ax0); ay0 = fmaf(w, r.y, ay0);
        az0 = fmaf(w, r.z, az0); aw0 = fmaf(w, r.w, aw0);
    }
    float4 a;
    a.x = ax0 + ax1; a.y = ay0 + ay1; a.z = az0 + az1; a.w = aw0 + aw1;
#pragma unroll
    for (int m = 64 / NG; m < 64; m <<= 1) {
        a.x += __shfl_xor(a.x, m); a.y += __shfl_xor(a.y, m);
        a.z += __shfl_xor(a.z, m); a.w += __shfl_xor(a.w, m);
    }
    return a;
}

// Gather 1: B[v] -= 2*dinv[v]*sum dinv[c]*C[c]  (in place)
__global__ void __launch_bounds__(BLK) k_gath1(const float* __restrict__ C,
                                               float* __restrict__ B,
                                               const float* __restrict__ dinv,
                                               const int* __restrict__ row_ptr,
                                               const int* __restrict__ sdst,
                                               int N) {
    int v = blockIdx.x * 4 + ((threadIdx.x) >> 6);
    if (v >= N) return;
    int lane = threadIdx.x & 63;
    int grp = lane >> 4, fl = lane & 15;
    float4 g = gatherT<4>(C, 64, dinv, sdst, row_ptr[v], row_ptr[v + 1], grp, fl);
    if (grp == 0) {
        float dv = -2.0f * dinv[v];
        float4 q = *(const float4*)(B + (size_t)v * 64 + 4 * fl);
        q.x = fmaf(dv, g.x, q.x); q.y = fmaf(dv, g.y, q.y);
        q.z = fmaf(dv, g.z, q.z); q.w = fmaf(dv, g.w, q.w);
        *(float4*)(B + (size_t)v * 64 + 4 * fl) = q;
    }
}

// Gather 2 (pure): C[v] = dropout(relu(D[v] + S(B)[v])).
// Shuffles for dropout words are executed by ALL lanes (no divergent shuffle).
__global__ void __launch_bounds__(BLK) k_gath2(const float* __restrict__ D,
                                               const float* __restrict__ B,
                                               float* __restrict__ C,
                                               const float* __restrict__ dinv,
                                               const int* __restrict__ row_ptr,
                                               const int* __restrict__ sdst,
                                               int N) {
    int v = blockIdx.x * 4 + ((threadIdx.x) >> 6);
    if (v >= N) return;
    int lane = threadIdx.x & 63;
    int grp = lane >> 4, fl = lane & 15;
    float4 g = gatherT<4>(B, 64, dinv, sdst, row_ptr[v], row_ptr[v + 1], grp, fl);
    unsigned w = tf_word((unsigned)v * 64u + (unsigned)lane);
    unsigned w0 = __shfl(w, 4 * fl + 0);
    unsigned w1 = __shfl(w, 4 * fl + 1);
    unsigned w2 = __shfl(w, 4 * fl + 2);
    unsigned w3 = __shfl(w, 4 * fl + 3);
    if (grp == 0) {
        float dv = -dinv[v];
        float4 d = *(const float4*)(D + (size_t)v * 64 + 4 * fl);
        float4 o;
        o.x = fmaxf(fmaf(dv, g.x, d.x), 0.0f);
        o.y = fmaxf(fmaf(dv, g.y, d.y), 0.0f);
        o.z = fmaxf(fmaf(dv, g.z, d.z), 0.0f);
        o.w = fmaxf(fmaf(dv, g.w, d.w), 0.0f);
        o.x = (w0 & 0x80000000u) ? 0.0f : o.x * 2.0f;
        o.y = (w1 & 0x80000000u) ? 0.0f : o.y * 2.0f;
        o.z = (w2 & 0x80000000u) ? 0.0f : o.z * 2.0f;
        o.w = (w3 & 0x80000000u) ? 0.0f : o.w * 2.0f;
        *(float4*)(C + (size_t)v * 64 + 4 * fl) = o;
    }
}

// Gather 3: R2 (C[.,32:64]) = D1 + 2*S(D2), D2 rows pitch 32 in B.
__global__ void __launch_bounds__(BLK) k_gath3(const float* __restrict__ B,
                                               float* __restrict__ C,
                                               const float* __restrict__ dinv,
                                               const int* __restrict__ row_ptr,
                                               const int* __restrict__ sdst,
                                               int N) {
    int v = blockIdx.x * 4 + ((threadIdx.x) >> 6);
    if (v >= N) return;
    int lane = threadIdx.x & 63;
    int grp = lane >> 3, fl = lane & 7;
    float4 g = gatherT<8>(B, 32, dinv, sdst, row_ptr[v], row_ptr[v + 1], grp, fl);
    if (grp == 0) {
        float dv = -2.0f * dinv[v];
        float* p = C + (size_t)v * 64 + 32 + 4 * fl;
        float4 q = *(const float4*)p;
        q.x = fmaf(dv, g.x, q.x); q.y = fmaf(dv, g.y, q.y);
        q.z = fmaf(dv, g.z, q.z); q.w = fmaf(dv, g.w, q.w);
        *(float4*)p = q;
    }
}

// Gather 4: out = log_softmax(D0 + b2 + S(R2)).
__global__ void __launch_bounds__(BLK) k_gath4(const float* __restrict__ C,
                                               const float* __restrict__ dinv,
                                               const int* __restrict__ row_ptr,
                                               const int* __restrict__ sdst,
                                               const float* __restrict__ b2,
                                               int N, float* __restrict__ out) {
    int v = blockIdx.x * 4 + ((threadIdx.x) >> 6);
    if (v >= N) return;
    int lane = threadIdx.x & 63;
    int grp = lane >> 3, fl = lane & 7;
    float4 g = gatherT<8>(C + 32, 64, dinv, sdst, row_ptr[v], row_ptr[v + 1], grp, fl);
    float dv = -dinv[v];
    float4 d0 = *(const float4*)(C + (size_t)v * 64 + 4 * fl);
    float4 bb = *(const float4*)(b2 + 4 * fl);
    float4 o;
    o.x = fmaf(dv, g.x, d0.x + bb.x);
    o.y = fmaf(dv, g.y, d0.y + bb.y);
    o.z = fmaf(dv, g.z, d0.z + bb.z);
    o.w = fmaf(dv, g.w, d0.w + bb.w);
    float m = fmaxf(fmaxf(o.x, o.y), fmaxf(o.z, o.w));
#pragma unroll
    for (int d = 1; d <= 4; d <<= 1) m = fmaxf(m, __shfl_xor(m, d));
    float s = expf(o.x - m) + expf(o.y - m) + expf(o.z - m) + expf(o.w - m);
#pragma unroll
    for (int d = 1; d <= 4; d <<= 1) s += __shfl_xor(s, d);
    float lse = m + logf(s);
    if (grp == 0) {
        float4 r;
        r.x = o.x - lse; r.y = o.y - lse; r.z = o.z - lse; r.w = o.w - lse;
        *(float4*)(out + (size_t)v * 32 + 4 * fl) = r;
    }
}

extern "C" void kernel_launch(void* const* d_in, const int* in_sizes, int n_in,
                              void* d_out, int out_size, void* d_ws, size_t ws_size,
                              hipStream_t stream) {
    const float* x  = (const float*)d_in[0];
    const int* ei   = (const int*)d_in[1];
    const float* W1 = (const float*)d_in[2];
    const float* b1 = (const float*)d_in[3];
    const float* W2 = (const float*)d_in[4];
    const float* b2 = (const float*)d_in[5];
    float* out = (float*)d_out;

    const int N = in_sizes[0] / 64;
    const int E = in_sizes[1] / 2;
    const int NB = (N + ROWB - 1) >> RB_SHIFT;

    char* ws = (char*)d_ws;
    size_t off = 0;
    auto alloc = [&](size_t bytes) -> void* {
        void* p = ws + off;
        off = (off + bytes + 511) & ~(size_t)511;
        return p;
    };
    int*      flags   = (int*)alloc(16);
    int*      deg     = (int*)alloc((size_t)N * 4);
    float*    dinv    = (float*)alloc((size_t)N * 4);
    int*      row_ptr = (int*)alloc(((size_t)N + 1) * 4);
    int*      blk_sum = (int*)alloc(4096);
    int*      bcnt    = (int*)alloc((size_t)NB * 4);
    // D aliases bdata: bdata (NB*BCAP*4 ~9.6 MB) is dead after k_place,
    // which completes before k_dense3 writes D (N*64*4 ~25.6 MB).
    size_t dbytes = (size_t)N * 64 * 4;
    size_t bdbytes = (size_t)NB * BCAP * 4;
    unsigned* bdata = (unsigned*)alloc(dbytes > bdbytes ? dbytes : bdbytes);
    float*    D     = (float*)bdata;
    int*      sdst    = (int*)alloc((size_t)E * 4);
    float*    B       = (float*)alloc((size_t)N * 64 * 4);
    float*    C       = (float*)alloc((size_t)N * 64 * 4);
    // total ~85 MB

    hipMemsetAsync(bcnt, 0, (size_t)NB * 4, stream);

    const int gN = (N + BLK - 1) / BLK;
    const int gW4 = (N + 3) / 4;
    const int gD = (N + 31) / 32;
    const int nb = (N + SCAN_CHUNK - 1) / SCAN_CHUNK;
    const int gBin = (E + CHUNK - 1) / CHUNK;

    k_detect<<<1, 256, 0, stream>>>(ei, flags);
    k_bin<<<gBin, 256, 0, stream>>>(ei, E, flags, bcnt, bdata, NB);
    k_hist2<<<NB, 256, 0, stream>>>(bdata, bcnt, N, deg);
    k_dinv<<<gN, BLK, 0, stream>>>(deg, N, dinv);
    k_scanA<<<nb, SCAN_CHUNK, 0, stream>>>(deg, N, blk_sum);
    k_scanB<<<1, 1024, 0, stream>>>(blk_sum, nb);
    k_scanC<<<nb, SCAN_CHUNK, 0, stream>>>(deg, N, E, blk_sum, row_ptr);
    k_place<<<NB, 256, 0, stream>>>(bdata, bcnt, row_ptr, N, sdst);

    // Layer 1: B=x@W1[1], C=x@W1[2], D=x@(W1[0]-W1[2])+b1;
    // B += 2*S(C); C = drop(relu(D + S(B)))
    k_dense3<<<gD, 256, 0, stream>>>(x, W1, b1, N, B, C, D);
    k_gath1<<<gW4, BLK, 0, stream>>>(C, B, dinv, row_ptr, sdst, N);
    k_gath2<<<gW4, BLK, 0, stream>>>(D, B, C, dinv, row_ptr, sdst, N);

    // Layer 2: D0,D1 in C; D2 in B; R2 = D1+2*S(D2); out = lsm(D0+b2+S(R2))
    k_dense3b<<<gD, 256, 0, stream>>>(W2, N, B, C);
    k_gath3<<<gW4, BLK, 0, stream>>>(B, C, dinv, row_ptr, sdst, N);
    k_gath4<<<gW4, BLK, 0, stream>>>(C, dinv, row_ptr, sdst, b2, N, out);
}

// Round 13
// 391.411 us; speedup vs baseline: 3.3054x; 1.1363x over previous
//
#include <hip/hip_runtime.h>

// ChebNet K=3, W-first form: ChebConv(H) = H@(W0-W2) + S·(H@W1 + 2·S·(H@W2)).
// Round 13: (1) k_dense3 at 512 threads / 64 nodes per block -> 16 waves/CU
// (was 8, Occupancy 18%); (2) gather-only intermediates (C, B, D2, R2) stored
// bf16 -> gather bytes halved, lane-groups widened (NG=8 / NG=16).

static constexpr int BLK = 256;
static constexpr int SCAN_CHUNK = 256;
static constexpr int ROWB = 256;
static constexpr int RB_SHIFT = 8;
static constexpr int BCAP = 6144;
static constexpr int CHUNK = 8192;

__device__ __forceinline__ unsigned rotl32(unsigned x, int r) {
    return (x << r) | (x >> (32 - r));
}

// JAX partitionable threefry word for element i:
// (b1,b2) = threefry2x32(key=(0,42), counter=(0,i)); word = b1 ^ b2.
__device__ __forceinline__ unsigned tf_word(unsigned i) {
    const unsigned ks0 = 0u;
    const unsigned ks1 = 42u;
    const unsigned ks2 = 0u ^ 42u ^ 0x1BD11BDAu;
    unsigned x0 = 0u + ks0;
    unsigned x1 = i + ks1;
#define TF_RND(r) { x0 += x1; x1 = rotl32(x1, (r)); x1 ^= x0; }
    TF_RND(13) TF_RND(15) TF_RND(26) TF_RND(6)
    x0 += ks1; x1 += ks2 + 1u;
    TF_RND(17) TF_RND(29) TF_RND(16) TF_RND(24)
    x0 += ks2; x1 += ks0 + 2u;
    TF_RND(13) TF_RND(15) TF_RND(26) TF_RND(6)
    x0 += ks0; x1 += ks1 + 3u;
    TF_RND(17) TF_RND(29) TF_RND(16) TF_RND(24)
    x0 += ks1; x1 += ks2 + 4u;
    TF_RND(13) TF_RND(15) TF_RND(26) TF_RND(6)
    x0 += ks2; x1 += ks0 + 5u;
#undef TF_RND
    return x0 ^ x1;
}

// bf16 pack/unpack
__device__ __forceinline__ float lo16(unsigned u) {
    union { unsigned x; float f; } c; c.x = u << 16; return c.f;
}
__device__ __forceinline__ float hi16(unsigned u) {
    union { unsigned x; float f; } c; c.x = u & 0xFFFF0000u; return c.f;
}
__device__ __forceinline__ unsigned short f2b(float f) {
    union { float f; unsigned u; } c; c.f = f;
    unsigned r = (c.u + 0x7FFFu + ((c.u >> 16) & 1u)) >> 16;
    return (unsigned short)r;
}
__device__ __forceinline__ unsigned pack2(float a, float b) {
    return (unsigned)f2b(a) | ((unsigned)f2b(b) << 16);
}

__global__ void k_detect(const int* __restrict__ ei, int* __restrict__ flags) {
    __shared__ int cnt_nz;
    int t = threadIdx.x;
    if (t == 0) cnt_nz = 0;
    __syncthreads();
    if (ei[2 * t + 1] != 0) atomicAdd(&cnt_nz, 1);
    __syncthreads();
    if (t == 0) flags[0] = (cnt_nz == 0) ? 1 : 0;
}

// Pass 1: bin edges into row-buckets, LDS-staged for coalesced writes.
__global__ void __launch_bounds__(256) k_bin(const int* __restrict__ ei, int E,
                                             const int* __restrict__ flags,
                                             int* __restrict__ bcnt,
                                             unsigned* __restrict__ bdata, int NB) {
    __shared__ unsigned sval[CHUNK];
    __shared__ unsigned short sbkt[CHUNK];
    __shared__ int h[512], ex[512], cur[512], basep[512];
    int t = threadIdx.x;
    int start = blockIdx.x * CHUNK;
    int lim = min(CHUNK, E - start);
    bool i64 = flags[0] != 0;
    h[t] = 0; h[t + 256] = 0;
    __syncthreads();
    unsigned vv[32];
    unsigned short bb_[32];
#pragma unroll
    for (int k = 0; k < 32; ++k) {
        int idx = k * 256 + t;
        int e = start + idx;
        if (idx < lim) {
            int r, c;
            if (i64) { r = ei[2 * e]; c = ei[2 * (E + e)]; }
            else     { r = ei[e];     c = ei[E + e]; }
            int b = r >> RB_SHIFT;
            vv[k] = ((unsigned)(r & (ROWB - 1)) << 17) | (unsigned)c;
            bb_[k] = (unsigned short)b;
            atomicAdd(&h[b], 1);
        } else {
            bb_[k] = 0xFFFF;
        }
    }
    __syncthreads();
    int i0 = t, i1 = t + 256;
    ex[i0] = h[i0]; ex[i1] = h[i1];
    __syncthreads();
    for (int off = 1; off < 512; off <<= 1) {
        int v0 = (i0 >= off) ? ex[i0 - off] : 0;
        int v1 = (i1 >= off) ? ex[i1 - off] : 0;
        __syncthreads();
        ex[i0] += v0; ex[i1] += v1;
        __syncthreads();
    }
    int e0 = ex[i0] - h[i0], e1 = ex[i1] - h[i1];
    __syncthreads();
    ex[i0] = e0; cur[i0] = e0;
    ex[i1] = e1; cur[i1] = e1;
    if (i0 < NB && h[i0] > 0) basep[i0] = atomicAdd(&bcnt[i0], h[i0]);
    if (i1 < NB && h[i1] > 0) basep[i1] = atomicAdd(&bcnt[i1], h[i1]);
    __syncthreads();
#pragma unroll
    for (int k = 0; k < 32; ++k) {
        if (bb_[k] != 0xFFFF) {
            int p = atomicAdd(&cur[bb_[k]], 1);
            sval[p] = vv[k];
            sbkt[p] = bb_[k];
        }
    }
    __syncthreads();
    for (int i = t; i < lim; i += 256) {
        int b = sbkt[i];
        int gpos = basep[b] + (i - ex[b]);
        if (gpos < BCAP) bdata[(size_t)b * BCAP + gpos] = sval[i];
    }
}

__global__ void __launch_bounds__(256) k_hist2(const unsigned* __restrict__ bdata,
                                               const int* __restrict__ bcnt,
                                               int N, int* __restrict__ deg) {
    __shared__ int h[ROWB];
    int t = threadIdx.x, b = blockIdx.x;
    h[t] = 0;
    __syncthreads();
    int cnt = min(bcnt[b], BCAP);
    for (int i = t; i < cnt; i += 256)
        atomicAdd(&h[bdata[(size_t)b * BCAP + i] >> 17], 1);
    __syncthreads();
    int r = b * ROWB + t;
    if (r < N) deg[r] = h[t];
}

__global__ void k_dinv(const int* __restrict__ deg, int N, float* __restrict__ dinv) {
    int v = blockIdx.x * blockDim.x + threadIdx.x;
    if (v < N) {
        int d = deg[v];
        dinv[v] = (d > 0) ? (1.0f / sqrtf((float)d)) : 0.0f;
    }
}

__global__ void k_scanA(const int* __restrict__ deg, int N, int* __restrict__ blk_sum) {
    __shared__ int lds[SCAN_CHUNK];
    int i = blockIdx.x * SCAN_CHUNK + threadIdx.x;
    int v = (i < N) ? deg[i] : 0;
    lds[threadIdx.x] = v;
    __syncthreads();
    for (int off = SCAN_CHUNK / 2; off > 0; off >>= 1) {
        if (threadIdx.x < off) lds[threadIdx.x] += lds[threadIdx.x + off];
        __syncthreads();
    }
    if (threadIdx.x == 0) blk_sum[blockIdx.x] = lds[0];
}

__global__ void k_scanB(int* __restrict__ blk_sum, int nb) {
    __shared__ int lds[1024];
    int t = threadIdx.x;
    int v = (t < nb) ? blk_sum[t] : 0;
    lds[t] = v;
    __syncthreads();
    for (int off = 1; off < 1024; off <<= 1) {
        int val = (t >= off) ? lds[t - off] : 0;
        __syncthreads();
        lds[t] += val;
        __syncthreads();
    }
    if (t < nb) blk_sum[t] = lds[t] - v;
}

__global__ void k_scanC(const int* __restrict__ deg, int N, int E,
                        const int* __restrict__ blk_sum, int* __restrict__ row_ptr) {
    __shared__ int lds[SCAN_CHUNK];
    int t = threadIdx.x;
    int i = blockIdx.x * SCAN_CHUNK + t;
    int v = (i < N) ? deg[i] : 0;
    lds[t] = v;
    __syncthreads();
    for (int off = 1; off < SCAN_CHUNK; off <<= 1) {
        int val = (t >= off) ? lds[t - off] : 0;
        __syncthreads();
        lds[t] += val;
        __syncthreads();
    }
    if (i < N) row_ptr[i] = blk_sum[blockIdx.x] + lds[t] - v;
    if (blockIdx.x == gridDim.x - 1 && t == SCAN_CHUNK - 1) row_ptr[N] = E;
}

__global__ void __launch_bounds__(256) k_place(const unsigned* __restrict__ bdata,
                                               const int* __restrict__ bcnt,
                                               const int* __restrict__ row_ptr,
                                               int N, int* __restrict__ sdst) {
    __shared__ int cur[ROWB];
    __shared__ int staged[BCAP];
    int t = threadIdx.x, b = blockIdx.x;
    int r0 = b * ROWB;
    int rbase = row_ptr[r0];
    int r = r0 + t;
    cur[t] = (r < N) ? (row_ptr[r] - rbase) : 0;
    __syncthreads();
    int cnt = min(bcnt[b], BCAP);
    for (int i = t; i < cnt; i += 256) {
        unsigned val = bdata[(size_t)b * BCAP + i];
        int p = atomicAdd(&cur[val >> 17], 1);
        staged[p] = (int)(val & 0x1FFFFu);
    }
    __syncthreads();
    for (int i = t; i < cnt; i += 256) sdst[rbase + i] = staged[i];
}

// W-stationary dense, layer 1. 512 threads, 64 nodes/block (8 waves/block,
// 2 blocks/CU -> 16 waves/CU). Outputs B16=bf16(x@W1[1]), C16=bf16(x@W1[2]),
// D=f32(x@(W1[0]-W1[2])+b1).
__global__ void __launch_bounds__(512) k_dense3(const float* __restrict__ x,
                                                const float* __restrict__ W1,
                                                const float* __restrict__ b1,
                                                int N,
                                                unsigned short* __restrict__ B16,
                                                unsigned short* __restrict__ C16,
                                                float* __restrict__ D) {
    __shared__ float sW1[4096], sW2[4096], sWd[4096], sx[4096], sb[64];
    int t = threadIdx.x;
    for (int i = t; i < 4096; i += 512) {
        float w0 = W1[i];
        float w2 = W1[8192 + i];
        sW1[i] = W1[4096 + i];
        sW2[i] = w2;
        sWd[i] = w0 - w2;
    }
    if (t < 64) sb[t] = b1[t];
    int v0 = blockIdx.x * 64;
    for (int i = t; i < 4096; i += 512) {
        int m = i >> 6, f = i & 63;
        int v = min(v0 + m, N - 1);
        sx[i] = x[(size_t)v * 64 + f];
    }
    __syncthreads();
    int wid = t >> 6, j = t & 63;
    float a0[8], a1[8], a2[8];
#pragma unroll
    for (int m = 0; m < 8; ++m) { a0[m] = 0.0f; a1[m] = 0.0f; a2[m] = sb[j]; }
    const float* xr = &sx[wid * 512];
#pragma unroll 2
    for (int k = 0; k < 64; ++k) {
        float w1v = sW1[k * 64 + j];
        float w2v = sW2[k * 64 + j];
        float wdv = sWd[k * 64 + j];
#pragma unroll
        for (int m = 0; m < 8; ++m) {
            float xk = xr[m * 64 + k];
            a0[m] = fmaf(xk, w1v, a0[m]);
            a1[m] = fmaf(xk, w2v, a1[m]);
            a2[m] = fmaf(xk, wdv, a2[m]);
        }
    }
#pragma unroll
    for (int m = 0; m < 8; ++m) {
        int v = v0 + wid * 8 + m;
        if (v < N) {
            size_t base = (size_t)v * 64 + j;
            B16[base] = f2b(a0[m]);
            C16[base] = f2b(a1[m]);
            D[base] = a2[m];
        }
    }
}

// W-stationary dense, layer 2. 256 threads, 32 nodes/block.
// D0=H@(W2[0]-W2[2]) -> C[.,0:32] f32; D1=H@W2[1] -> C[.,32:64] f32;
// D2=H@W2[2] -> B16 bf16 pitch 32.
__global__ void __launch_bounds__(256) k_dense3b(const float* __restrict__ W2,
                                                 int N,
                                                 unsigned short* __restrict__ B16,
                                                 float* __restrict__ C) {
    __shared__ float sWd[2048], sW1[2048], sW2[2048], sx[2048];
    int t = threadIdx.x;
    for (int i = t; i < 2048; i += 256) {
        float w0 = W2[i];
        float w2 = W2[4096 + i];
        sWd[i] = w0 - w2;
        sW1[i] = W2[2048 + i];
        sW2[i] = w2;
    }
    int v0 = blockIdx.x * 32;
    for (int i = t; i < 2048; i += 256) {
        int m = i >> 6, f = i & 63;
        int v = min(v0 + m, N - 1);
        sx[i] = C[(size_t)v * 64 + f];
    }
    __syncthreads();
    int wid = t >> 6;
    int lane = t & 63;
    int half = lane >> 5, jc = lane & 31;
    float d0[4], d1[4], d2[4];
#pragma unroll
    for (int m = 0; m < 4; ++m) { d0[m] = 0.0f; d1[m] = 0.0f; d2[m] = 0.0f; }
#pragma unroll 2
    for (int k = 0; k < 64; ++k) {
        float wdv = sWd[k * 32 + jc];
        float w1v = sW1[k * 32 + jc];
        float w2v = sW2[k * 32 + jc];
#pragma unroll
        for (int m = 0; m < 4; ++m) {
            float xk = sx[(wid * 8 + 2 * m + half) * 64 + k];
            d0[m] = fmaf(xk, wdv, d0[m]);
            d1[m] = fmaf(xk, w1v, d1[m]);
            d2[m] = fmaf(xk, w2v, d2[m]);
        }
    }
#pragma unroll
    for (int m = 0; m < 4; ++m) {
        int v = v0 + wid * 8 + 2 * m + half;
        if (v < N) {
            size_t base = (size_t)v * 64;
            C[base + jc] = d0[m];
            C[base + 32 + jc] = d1[m];
            B16[(size_t)v * 32 + jc] = f2b(d2[m]);
        }
    }
}

// bf16 lane-split gather: NG groups of 64/NG lanes; each lane loads 8 bf16
// (16 B) at src[c*pitch + 8*fl]; xor-reduce over group bits leaves full row
// sums in a[0..7] for all lanes.
template <int NG>
__device__ __forceinline__ void gatherB(const unsigned short* __restrict__ src,
                                        int pitch,
                                        const float* __restrict__ dinv,
                                        const int* __restrict__ sdst,
                                        int beg, int end, int grp, int fl,
                                        float a[8]) {
#pragma unroll
    for (int q = 0; q < 8; ++q) a[q] = 0.0f;
    int e = beg + grp;
    for (; e + NG < end; e += 2 * NG) {
        int c0 = sdst[e];
        int c1 = sdst[e + NG];
        float w0 = dinv[c0], w1 = dinv[c1];
        uint4 r0 = *(const uint4*)(src + (size_t)c0 * pitch + 8 * fl);
        uint4 r1 = *(const uint4*)(src + (size_t)c1 * pitch + 8 * fl);
        a[0] = fmaf(w0, lo16(r0.x), a[0]); a[1] = fmaf(w0, hi16(r0.x), a[1]);
        a[2] = fmaf(w0, lo16(r0.y), a[2]); a[3] = fmaf(w0, hi16(r0.y), a[3]);
        a[4] = fmaf(w0, lo16(r0.z), a[4]); a[5] = fmaf(w0, hi16(r0.z), a[5]);
        a[6] = fmaf(w0, lo16(r0.w), a[6]); a[7] = fmaf(w0, hi16(r0.w), a[7]);
        a[0] = fmaf(w1, lo16(r1.x), a[0]); a[1] = fmaf(w1, hi16(r1.x), a[1]);
        a[2] = fmaf(w1, lo16(r1.y), a[2]); a[3] = fmaf(w1, hi16(r1.y), a[3]);
        a[4] = fmaf(w1, lo16(r1.z), a[4]); a[5] = fmaf(w1, hi16(r1.z), a[5]);
        a[6] = fmaf(w1, lo16(r1.w), a[6]); a[7] = fmaf(w1, hi16(r1.w), a[7]);
    }
    if (e < end) {
        int c = sdst[e];
        float w = dinv[c];
        uint4 r = *(const uint4*)(src + (size_t)c * pitch + 8 * fl);
        a[0] = fmaf(w, lo16(r.x), a[0]); a[1] = fmaf(w, hi16(r.x), a[1]);
        a[2] = fmaf(w, lo16(r.y), a[2]); a[3] = fmaf(w, hi16(r.y), a[3]);
        a[4] = fmaf(w, lo16(r.z), a[4]); a[5] = fmaf(w, hi16(r.z), a[5]);
        a[6] = fmaf(w, lo16(r.w), a[6]); a[7] = fmaf(w, hi16(r.w), a[7]);
    }
#pragma unroll
    for (int m = 64 / NG; m < 64; m <<= 1) {
#pragma unroll
        for (int q = 0; q < 8; ++q) a[q] += __shfl_xor(a[q], m);
    }
}

// Gather 1: B16[v] = bf16( B16[v] - 2*dinv[v]*sum dinv[c]*C16[c] )
__global__ void __launch_bounds__(BLK) k_gath1(const unsigned short* __restrict__ C16,
                                               unsigned short* __restrict__ B16,
                                               const float* __restrict__ dinv,
                                               const int* __restrict__ row_ptr,
                                               const int* __restrict__ sdst,
                                               int N) {
    int v = blockIdx.x * 4 + (threadIdx.x >> 6);
    if (v >= N) return;
    int lane = threadIdx.x & 63;
    int grp = lane >> 3, fl = lane & 7;
    float a[8];
    gatherB<8>(C16, 64, dinv, sdst, row_ptr[v], row_ptr[v + 1], grp, fl, a);
    if (grp == 0) {
        float dv = -2.0f * dinv[v];
        unsigned short* p = B16 + (size_t)v * 64 + 8 * fl;
        uint4 b = *(const uint4*)p;
        float q0 = fmaf(dv, a[0], lo16(b.x)), q1 = fmaf(dv, a[1], hi16(b.x));
        float q2 = fmaf(dv, a[2], lo16(b.y)), q3 = fmaf(dv, a[3], hi16(b.y));
        float q4 = fmaf(dv, a[4], lo16(b.z)), q5 = fmaf(dv, a[5], hi16(b.z));
        float q6 = fmaf(dv, a[6], lo16(b.w)), q7 = fmaf(dv, a[7], hi16(b.w));
        uint4 o;
        o.x = pack2(q0, q1); o.y = pack2(q2, q3);
        o.z = pack2(q4, q5); o.w = pack2(q6, q7);
        *(uint4*)p = o;
    }
}

// Gather 2: C[v] (f32 H) = dropout(relu(D[v] + S(B16)[v])).
// Dropout-word shuffles executed by ALL lanes.
__global__ void __launch_bounds__(BLK) k_gath2(const float* __restrict__ D,
                                               const unsigned short* __restrict__ B16,
                                               float* __restrict__ C,
                                               const float* __restrict__ dinv,
                                               const int* __restrict__ row_ptr,
                                               const int* __restrict__ sdst,
                                               int N) {
    int v = blockIdx.x * 4 + (threadIdx.x >> 6);
    if (v >= N) return;
    int lane = threadIdx.x & 63;
    int grp = lane >> 3, fl = lane & 7;
    float a[8];
    gatherB<8>(B16, 64, dinv, sdst, row_ptr[v], row_ptr[v + 1], grp, fl, a);
    unsigned w = tf_word((unsigned)v * 64u + (unsigned)lane);
    unsigned ww[8];
#pragma unroll
    for (int k = 0; k < 8; ++k) ww[k] = __shfl(w, 8 * fl + k);
    if (grp == 0) {
        float dv = -dinv[v];
        const float* dp = D + (size_t)v * 64 + 8 * fl;
        float4 dA = *(const float4*)dp;
        float4 dB = *(const float4*)(dp + 4);
        float o[8];
        o[0] = fmaxf(fmaf(dv, a[0], dA.x), 0.0f);
        o[1] = fmaxf(fmaf(dv, a[1], dA.y), 0.0f);
        o[2] = fmaxf(fmaf(dv, a[2], dA.z), 0.0f);
        o[3] = fmaxf(fmaf(dv, a[3], dA.w), 0.0f);
        o[4] = fmaxf(fmaf(dv, a[4], dB.x), 0.0f);
        o[5] = fmaxf(fmaf(dv, a[5], dB.y), 0.0f);
        o[6] = fmaxf(fmaf(dv, a[6], dB.z), 0.0f);
        o[7] = fmaxf(fmaf(dv, a[7], dB.w), 0.0f);
#pragma unroll
        for (int k = 0; k < 8; ++k)
            o[k] = (ww[k] & 0x80000000u) ? 0.0f : o[k] * 2.0f;
        float* cp = C + (size_t)v * 64 + 8 * fl;
        *(float4*)cp = make_float4(o[0], o[1], o[2], o[3]);
        *(float4*)(cp + 4) = make_float4(o[4], o[5], o[6], o[7]);
    }
}

// Gather 3: R16[v] = bf16( D1[v] - 2*dinv[v]*sum dinv[c]*D2[c] ), D2 in B16 pitch 32.
__global__ void __launch_bounds__(BLK) k_gath3(const unsigned short* __restrict__ B16,
                                               const float* __restrict__ C,
                                               unsigned short* __restrict__ R16,
                                               const float* __restrict__ dinv,
                                               const int* __restrict__ row_ptr,
                                               const int* __restrict__ sdst,
                                               int N) {
    int v = blockIdx.x * 4 + (threadIdx.x >> 6);
    if (v >= N) return;
    int lane = threadIdx.x & 63;
    int grp = lane >> 2, fl = lane & 3;
    float a[8];
    gatherB<16>(B16, 32, dinv, sdst, row_ptr[v], row_ptr[v + 1], grp, fl, a);
    if (grp == 0) {
        float dv = -2.0f * dinv[v];
        const float* dp = C + (size_t)v * 64 + 32 + 8 * fl;
        float4 dA = *(const float4*)dp;
        float4 dB = *(const float4*)(dp + 4);
        uint4 o;
        o.x = pack2(fmaf(dv, a[0], dA.x), fmaf(dv, a[1], dA.y));
        o.y = pack2(fmaf(dv, a[2], dA.z), fmaf(dv, a[3], dA.w));
        o.z = pack2(fmaf(dv, a[4], dB.x), fmaf(dv, a[5], dB.y));
        o.w = pack2(fmaf(dv, a[6], dB.z), fmaf(dv, a[7], dB.w));
        *(uint4*)(R16 + (size_t)v * 32 + 8 * fl) = o;
    }
}

// Gather 4: out = log_softmax(D0 + b2 + S(R16)).
__global__ void __launch_bounds__(BLK) k_gath4(const unsigned short* __restrict__ R16,
                                               const float* __restrict__ C,
                                               const float* __restrict__ dinv,
                                               const int* __restrict__ row_ptr,
                                               const int* __restrict__ sdst,
                                               const float* __restrict__ b2,
                                               int N, float* __restrict__ out) {
    int v = blockIdx.x * 4 + (threadIdx.x >> 6);
    if (v >= N) return;
    int lane = threadIdx.x & 63;
    int grp = lane >> 2, fl = lane & 3;
    float a[8];
    gatherB<16>(R16, 32, dinv, sdst, row_ptr[v], row_ptr[v + 1], grp, fl, a);
    float dv = -dinv[v];
    const float* dp = C + (size_t)v * 64 + 8 * fl;
    float4 dA = *(const float4*)dp;
    float4 dB = *(const float4*)(dp + 4);
    const float* bp = b2 + 8 * fl;
    float4 bA = *(const float4*)bp;
    float4 bB = *(const float4*)(bp + 4);
    float o[8];
    o[0] = fmaf(dv, a[0], dA.x + bA.x);
    o[1] = fmaf(dv, a[1], dA.y + bA.y);
    o[2] = fmaf(dv, a[2], dA.z + bA.z);
    o[3] = fmaf(dv, a[3], dA.w + bA.w);
    o[4] = fmaf(dv, a[4], dB.x + bB.x);
    o[5] = fmaf(dv, a[5], dB.y + bB.y);
    o[6] = fmaf(dv, a[6], dB.z + bB.z);
    o[7] = fmaf(dv, a[7], dB.w + bB.w);
    float m = o[0];
#pragma unroll
    for (int k = 1; k < 8; ++k) m = fmaxf(m, o[k]);
    m = fmaxf(m, __shfl_xor(m, 1));
    m = fmaxf(m, __shfl_xor(m, 2));
    float s = 0.0f;
#pragma unroll
    for (int k = 0; k < 8; ++k) s += expf(o[k] - m);
    s += __shfl_xor(s, 1);
    s += __shfl_xor(s, 2);
    float lse = m + logf(s);
    if (grp == 0) {
        float* op = out + (size_t)v * 32 + 8 * fl;
        *(float4*)op = make_float4(o[0] - lse, o[1] - lse, o[2] - lse, o[3] - lse);
        *(float4*)(op + 4) = make_float4(o[4] - lse, o[5] - lse, o[6] - lse, o[7] - lse);
    }
}

extern "C" void kernel_launch(void* const* d_in, const int* in_sizes, int n_in,
                              void* d_out, int out_size, void* d_ws, size_t ws_size,
                              hipStream_t stream) {
    const float* x  = (const float*)d_in[0];
    const int* ei   = (const int*)d_in[1];
    const float* W1 = (const float*)d_in[2];
    const float* b1 = (const float*)d_in[3];
    const float* W2 = (const float*)d_in[4];
    const float* b2 = (const float*)d_in[5];
    float* out = (float*)d_out;

    const int N = in_sizes[0] / 64;
    const int E = in_sizes[1] / 2;
    const int NB = (N + ROWB - 1) >> RB_SHIFT;

    char* ws = (char*)d_ws;
    size_t off = 0;
    auto alloc = [&](size_t bytes) -> void* {
        void* p = ws + off;
        off = (off + bytes + 511) & ~(size_t)511;
        return p;
    };
    int*      flags   = (int*)alloc(16);
    int*      deg     = (int*)alloc((size_t)N * 4);
    float*    dinv    = (float*)alloc((size_t)N * 4);
    int*      row_ptr = (int*)alloc(((size_t)N + 1) * 4);
    int*      blk_sum = (int*)alloc(4096);
    int*      bcnt    = (int*)alloc((size_t)NB * 4);
    // D (f32 N*64, 25.6 MB) aliases bdata (9.6 MB, dead after k_place).
    size_t dbytes = (size_t)N * 64 * 4;
    size_t bdbytes = (size_t)NB * BCAP * 4;
    unsigned* bdata = (unsigned*)alloc(dbytes > bdbytes ? dbytes : bdbytes);
    float*    D     = (float*)bdata;
    int*      sdst  = (int*)alloc((size_t)E * 4);
    float*    C     = (float*)alloc((size_t)N * 64 * 4);
    unsigned short* B16 = (unsigned short*)alloc((size_t)N * 64 * 2);
    // C16 (layer-1 gather source, dead after gath1) shares with R16 (layer-2).
    unsigned short* C16 = (unsigned short*)alloc((size_t)N * 64 * 2);
    unsigned short* R16 = C16;
    // total ~84 MB

    hipMemsetAsync(bcnt, 0, (size_t)NB * 4, stream);

    const int gN = (N + BLK - 1) / BLK;
    const int gW4 = (N + 3) / 4;
    const int gD3 = (N + 63) / 64;
    const int gD2 = (N + 31) / 32;
    const int nb = (N + SCAN_CHUNK - 1) / SCAN_CHUNK;
    const int gBin = (E + CHUNK - 1) / CHUNK;

    k_detect<<<1, 256, 0, stream>>>(ei, flags);
    k_bin<<<gBin, 256, 0, stream>>>(ei, E, flags, bcnt, bdata, NB);
    k_hist2<<<NB, 256, 0, stream>>>(bdata, bcnt, N, deg);
    k_dinv<<<gN, BLK, 0, stream>>>(deg, N, dinv);
    k_scanA<<<nb, SCAN_CHUNK, 0, stream>>>(deg, N, blk_sum);
    k_scanB<<<1, 1024, 0, stream>>>(blk_sum, nb);
    k_scanC<<<nb, SCAN_CHUNK, 0, stream>>>(deg, N, E, blk_sum, row_ptr);
    k_place<<<NB, 256, 0, stream>>>(bdata, bcnt, row_ptr, N, sdst);

    // Layer 1: B16=bf16(x@W1[1]), C16=bf16(x@W1[2]), D=x@(W1[0]-W1[2])+b1;
    // B16 += 2*S(C16); C = drop(relu(D + S(B16)))
    k_dense3<<<gD3, 512, 0, stream>>>(x, W1, b1, N, B16, C16, D);
    k_gath1<<<gW4, BLK, 0, stream>>>(C16, B16, dinv, row_ptr, sdst, N);
    k_gath2<<<gW4, BLK, 0, stream>>>(D, B16, C, dinv, row_ptr, sdst, N);

    // Layer 2: D0,D1 f32 in C; D2 bf16 in B16 (pitch 32);
    // R16 = bf16(D1 + 2*S(D2)); out = lsm(D0 + b2 + S(R16))
    k_dense3b<<<gD2, 256, 0, stream>>>(W2, N, B16, C);
    k_gath3<<<gW4, BLK, 0, stream>>>(B16, C, R16, dinv, row_ptr, sdst, N);
    k_gath4<<<gW4, BLK, 0, stream>>>(R16, C, dinv, row_ptr, sdst, b2, N, out);
}